// Round 1
// baseline (719.902 us; speedup 1.0000x reference)
//
#include <hip/hip_runtime.h>
#include <math.h>

#define NEG_INF -10000.0f

static constexpr int Dm = 256;   // model dim
static constexpr int Lm = 256;   // residues
static constexpr int Sm = 128;   // sequences
static constexpr int Mrows = Sm * Lm;  // 32768 rows of the (M, D) activations

// ---------------------------------------------------------------------------
// 1) LayerNorm statistics: one wave per row, stats[row] = (mu, rsqrt(var+eps))
// ---------------------------------------------------------------------------
__global__ __launch_bounds__(256)
void ln_stats_kernel(const float* __restrict__ m, float* __restrict__ stats) {
    const int wid = threadIdx.x >> 6;
    const int lane = threadIdx.x & 63;
    const int row = (blockIdx.x << 2) + wid;
    const float4* m4 = (const float4*)(m + (size_t)row * Dm);
    float4 a = m4[lane];                         // 64 lanes x 4 = 256 elems
    float s  = a.x + a.y + a.z + a.w;
    float ss = a.x*a.x + a.y*a.y + a.z*a.z + a.w*a.w;
    #pragma unroll
    for (int o = 32; o > 0; o >>= 1) {
        s  += __shfl_down(s, o);
        ss += __shfl_down(ss, o);
    }
    if (lane == 0) {
        float mu  = s * (1.0f / 256.0f);
        float var = ss * (1.0f / 256.0f) - mu * mu;
        float2 st;
        st.x = mu;
        st.y = rsqrtf(var + 1e-5f);
        ((float2*)stats)[row] = st;
    }
}

// ---------------------------------------------------------------------------
// 2) Mask decode: robust to int32 / float32 / byte encodings of the bool masks.
//    seqflag[q] = seq_pad[q] ? 1 : 0 ;  kbias[k] = res_pad[k] ? NEG_INF : 0
// ---------------------------------------------------------------------------
__global__ void mask_decode_kernel(const unsigned* __restrict__ seq_raw,
                                   const unsigned* __restrict__ res_raw,
                                   float* __restrict__ seqflag,
                                   float* __restrict__ kbias) {
    __shared__ unsigned long long sb[4], sf[4];
    __shared__ int enc;   // 0 = int32, 1 = float32, 2 = byte
    const int t = threadIdx.x;

    // Inspect first 64 words of each array (256 bytes — safe under all encodings).
    unsigned w = 0;
    if (t < 64)        w = seq_raw[t];
    else if (t < 128)  w = res_raw[t - 64];
    bool bad = (w != 0u) && (w != 1u) && (w != 0x3f800000u);
    bool isf = (w == 0x3f800000u);
    unsigned long long bm = __ballot(bad);
    unsigned long long fm = __ballot(isf);
    const int wid = t >> 6;
    if ((t & 63) == 0) { sb[wid] = bm; sf[wid] = fm; }
    __syncthreads();
    if (t == 0) {
        unsigned long long B = sb[0] | sb[1];
        unsigned long long F = sf[0] | sf[1];
        enc = B ? 2 : (F ? 1 : 0);
    }
    __syncthreads();
    const int e = enc;
    int sv, rv;
    if (e == 2) {
        const unsigned char* sp = (const unsigned char*)seq_raw;
        const unsigned char* rp = (const unsigned char*)res_raw;
        sv = sp[t]; rv = rp[t];
    } else if (e == 1) {
        sv = (((const float*)seq_raw)[t] != 0.0f);
        rv = (((const float*)res_raw)[t] != 0.0f);
    } else {
        sv = (seq_raw[t] != 0u);
        rv = (res_raw[t] != 0u);
    }
    seqflag[t] = sv ? 1.0f : 0.0f;
    kbias[t]   = rv ? NEG_INF : 0.0f;
}

// ---------------------------------------------------------------------------
// 3) Tiled fp32 GEMM: out[m,n] = (op over k) A'[m,k] * W[n,k]   (+ epilogue)
//    A' = LN(A) when stats != nullptr. Tile 64x64, BK=16, 4x4 regs/thread.
//    sigm=1 -> out = sigmoid(acc + bias). else out = acc*scale (+bias).
// ---------------------------------------------------------------------------
__global__ __launch_bounds__(256)
void gemm256_kernel(const float* __restrict__ A, const float* __restrict__ W,
                    const float* __restrict__ stats, const float* __restrict__ lng,
                    const float* __restrict__ lnb, const float* __restrict__ bias,
                    float* __restrict__ out, float scale, int sigm) {
    __shared__ float As[16][64];
    __shared__ float Bs[16][64];
    const int tid = threadIdx.x;
    const int tx = tid & 15, ty = tid >> 4;
    const int m0 = blockIdx.y << 6, n0 = blockIdx.x << 6;
    const int lrow = tid >> 2;            // 0..63
    const int lk4  = (tid & 3) << 2;      // 0,4,8,12
    const bool ln = (stats != nullptr);
    float mu = 0.0f, rs = 0.0f;
    if (ln) {
        float2 st = ((const float2*)stats)[m0 + lrow];
        mu = st.x; rs = st.y;
    }
    float acc[4][4];
    #pragma unroll
    for (int i = 0; i < 4; ++i)
        #pragma unroll
        for (int j = 0; j < 4; ++j) acc[i][j] = 0.0f;

    const float* Arow = A + (size_t)(m0 + lrow) * Dm;
    const float* Wrow = W + (size_t)(n0 + lrow) * Dm;

    for (int kt = 0; kt < Dm; kt += 16) {
        float4 av = *(const float4*)(Arow + kt + lk4);
        if (ln) {
            float4 gv = *(const float4*)(lng + kt + lk4);
            float4 bv = *(const float4*)(lnb + kt + lk4);
            av.x = (av.x - mu) * rs * gv.x + bv.x;
            av.y = (av.y - mu) * rs * gv.y + bv.y;
            av.z = (av.z - mu) * rs * gv.z + bv.z;
            av.w = (av.w - mu) * rs * gv.w + bv.w;
        }
        float4 wv = *(const float4*)(Wrow + kt + lk4);
        As[lk4 + 0][lrow] = av.x; As[lk4 + 1][lrow] = av.y;
        As[lk4 + 2][lrow] = av.z; As[lk4 + 3][lrow] = av.w;
        Bs[lk4 + 0][lrow] = wv.x; Bs[lk4 + 1][lrow] = wv.y;
        Bs[lk4 + 2][lrow] = wv.z; Bs[lk4 + 3][lrow] = wv.w;
        __syncthreads();
        #pragma unroll
        for (int kk = 0; kk < 16; ++kk) {
            float4 af = *(const float4*)&As[kk][ty << 2];
            float4 bf = *(const float4*)&Bs[kk][tx << 2];
            acc[0][0] += af.x * bf.x; acc[0][1] += af.x * bf.y;
            acc[0][2] += af.x * bf.z; acc[0][3] += af.x * bf.w;
            acc[1][0] += af.y * bf.x; acc[1][1] += af.y * bf.y;
            acc[1][2] += af.y * bf.z; acc[1][3] += af.y * bf.w;
            acc[2][0] += af.z * bf.x; acc[2][1] += af.z * bf.y;
            acc[2][2] += af.z * bf.z; acc[2][3] += af.z * bf.w;
            acc[3][0] += af.w * bf.x; acc[3][1] += af.w * bf.y;
            acc[3][2] += af.w * bf.z; acc[3][3] += af.w * bf.w;
        }
        __syncthreads();
    }
    #pragma unroll
    for (int i = 0; i < 4; ++i) {
        const int row = m0 + (ty << 2) + i;
        float4 ov;
        ov.x = acc[i][0] * scale; ov.y = acc[i][1] * scale;
        ov.z = acc[i][2] * scale; ov.w = acc[i][3] * scale;
        if (bias) {
            float4 bv = *(const float4*)(bias + n0 + (tx << 2));
            ov.x += bv.x; ov.y += bv.y; ov.z += bv.z; ov.w += bv.w;
        }
        if (sigm) {
            ov.x = 1.0f / (1.0f + __expf(-ov.x));
            ov.y = 1.0f / (1.0f + __expf(-ov.y));
            ov.z = 1.0f / (1.0f + __expf(-ov.z));
            ov.w = 1.0f / (1.0f + __expf(-ov.w));
        }
        *(float4*)(out + (size_t)row * Dm + n0 + (tx << 2)) = ov;
    }
}

// ---------------------------------------------------------------------------
// 4) Attention: one block per (s,h). K,V staged in LDS (64 KB). Thread t =
//    query t; online softmax over 256 keys; gated output written to o buffer.
// ---------------------------------------------------------------------------
__global__ __launch_bounds__(256)
void attn_kernel(const float* __restrict__ qg, const float* __restrict__ kg,
                 const float* __restrict__ vg, const float* __restrict__ gg,
                 const float* __restrict__ seqflag, const float* __restrict__ kbias,
                 float* __restrict__ og) {
    __shared__ float4 Kl[Lm * 8];   // 32 KB
    __shared__ float4 Vl[Lm * 8];   // 32 KB
    const int h = blockIdx.x;
    const int s = blockIdx.y;
    const int t = threadIdx.x;      // query index
    const int c8 = t & 7;
    const int r0 = t >> 3;
    // float4 offset of row 0 (head h) within this s: ((s*256 + r)*256 + h*32)/4
    const size_t b4 = (size_t)s * Lm * 64 + h * 8;
    const float4* k4 = (const float4*)kg;
    const float4* v4 = (const float4*)vg;
    #pragma unroll
    for (int i = 0; i < 8; ++i) {
        int r = r0 + (i << 5);
        Kl[(r << 3) + c8] = k4[b4 + (size_t)r * 64 + c8];
        Vl[(r << 3) + c8] = v4[b4 + (size_t)r * 64 + c8];
    }
    const size_t qofs = b4 + (size_t)t * 64;
    const float4* q4 = (const float4*)qg;
    float4 qf[8];
    #pragma unroll
    for (int i = 0; i < 8; ++i) qf[i] = q4[qofs + i];
    const bool allneg = (seqflag[t] != 0.0f);
    __syncthreads();

    float mrun = -INFINITY, lsum = 0.0f;
    float4 acc[8];
    #pragma unroll
    for (int i = 0; i < 8; ++i) acc[i] = make_float4(0.f, 0.f, 0.f, 0.f);

    for (int kk = 0; kk < Lm; ++kk) {
        const float4* kr = &Kl[kk << 3];
        float dot = 0.0f;
        #pragma unroll
        for (int i = 0; i < 8; ++i) {
            float4 kv = kr[i];
            dot += qf[i].x * kv.x; dot += qf[i].y * kv.y;
            dot += qf[i].z * kv.z; dot += qf[i].w * kv.w;
        }
        float bias = allneg ? NEG_INF : kbias[kk];
        float sc = dot + bias;
        float mnew = fmaxf(mrun, sc);
        float alpha = __expf(mrun - mnew);   // exp(-inf)=0 on first iter
        float p = __expf(sc - mnew);
        lsum = lsum * alpha + p;
        const float4* vr = &Vl[kk << 3];
        #pragma unroll
        for (int i = 0; i < 8; ++i) {
            float4 vv = vr[i];
            acc[i].x = acc[i].x * alpha + p * vv.x;
            acc[i].y = acc[i].y * alpha + p * vv.y;
            acc[i].z = acc[i].z * alpha + p * vv.z;
            acc[i].w = acc[i].w * alpha + p * vv.w;
        }
        mrun = mnew;
    }
    const float inv = 1.0f / lsum;
    const float4* g4 = (const float4*)gg;
    float4* o4 = (float4*)og;
    #pragma unroll
    for (int i = 0; i < 8; ++i) {
        float4 gv = g4[qofs + i];
        float4 ov;
        ov.x = acc[i].x * inv * gv.x;
        ov.y = acc[i].y * inv * gv.y;
        ov.z = acc[i].z * inv * gv.z;
        ov.w = acc[i].w * inv * gv.w;
        o4[qofs + i] = ov;
    }
}

// ---------------------------------------------------------------------------
// Launch
// ---------------------------------------------------------------------------
extern "C" void kernel_launch(void* const* d_in, const int* in_sizes, int n_in,
                              void* d_out, int out_size, void* d_ws, size_t ws_size,
                              hipStream_t stream) {
    const float* m    = (const float*)d_in[0];
    const unsigned* seqp = (const unsigned*)d_in[1];
    const unsigned* resp = (const unsigned*)d_in[2];
    const float* lng  = (const float*)d_in[3];
    const float* lnb  = (const float*)d_in[4];
    const float* Wq   = (const float*)d_in[5];
    const float* Wk   = (const float*)d_in[6];
    const float* Wv   = (const float*)d_in[7];
    const float* Wg   = (const float*)d_in[8];
    const float* bg   = (const float*)d_in[9];
    const float* Wo   = (const float*)d_in[10];
    const float* bo   = (const float*)d_in[11];
    float* out = (float*)d_out;

    float* ws = (float*)d_ws;
    float* stats   = ws;                 // 32768 * 2
    float* seqflag = ws + 65536;         // 256
    float* kbias   = ws + 65792;         // 256
    float* qb = ws + 66048;              // 5 buffers of 32768*256 floats
    const size_t BUF = (size_t)Mrows * Dm;   // 8388608
    float* kb = qb + BUF;
    float* vb = kb + BUF;
    float* gb = vb + BUF;
    float* ob = gb + BUF;

    ln_stats_kernel<<<Mrows / 4, 256, 0, stream>>>(m, stats);
    mask_decode_kernel<<<1, 256, 0, stream>>>(seqp, resp, seqflag, kbias);

    const dim3 gemm_grid(Dm / 64, Mrows / 64);   // (4, 512)
    const float qscale = 0.17677669529663687f;   // 1/sqrt(32)
    gemm256_kernel<<<gemm_grid, 256, 0, stream>>>(m, Wq, stats, lng, lnb, nullptr, qb, qscale, 0);
    gemm256_kernel<<<gemm_grid, 256, 0, stream>>>(m, Wk, stats, lng, lnb, nullptr, kb, 1.0f, 0);
    gemm256_kernel<<<gemm_grid, 256, 0, stream>>>(m, Wv, stats, lng, lnb, nullptr, vb, 1.0f, 0);
    gemm256_kernel<<<gemm_grid, 256, 0, stream>>>(m, Wg, stats, lng, lnb, bg,      gb, 1.0f, 1);

    attn_kernel<<<dim3(8, Sm), 256, 0, stream>>>(qb, kb, vb, gb, seqflag, kbias, ob);

    gemm256_kernel<<<gemm_grid, 256, 0, stream>>>(ob, Wo, nullptr, nullptr, nullptr, bo, out, 1.0f, 0);
}

// Round 2
// 279.926 us; speedup vs baseline: 2.5718x; 2.5718x over previous
//
#include <hip/hip_runtime.h>
#include <math.h>

#define NEG_INF -10000.0f

typedef short bf16x8 __attribute__((ext_vector_type(8)));
typedef float f32x4 __attribute__((ext_vector_type(4)));

static constexpr int Dm = 256;   // model dim
static constexpr int Lm = 256;   // residues
static constexpr int Sm = 128;   // sequences
static constexpr int Mrows = Sm * Lm;  // 32768

__device__ __forceinline__ ushort f2bf(float x) {
    unsigned u = __float_as_uint(x);
    unsigned r = (u + 0x7FFFu + ((u >> 16) & 1u)) >> 16;
    return (ushort)r;
}
__device__ __forceinline__ float bf2f(ushort h) {
    return __uint_as_float(((unsigned)h) << 16);
}
__device__ __forceinline__ void gload_lds16(const void* g, void* l) {
    __builtin_amdgcn_global_load_lds((__attribute__((address_space(1))) void*)g,
                                     (__attribute__((address_space(3))) void*)l,
                                     16, 0, 0);
}
__device__ __forceinline__ f32x4 mfma16(bf16x8 a, bf16x8 b, f32x4 c) {
    return __builtin_amdgcn_mfma_f32_16x16x32_bf16(a, b, c, 0, 0, 0);
}

// ---------------------------------------------------------------------------
// LN + split activations into bf16 hi/lo. One wave per row.
// ---------------------------------------------------------------------------
__global__ __launch_bounds__(256)
void a_prep(const float* __restrict__ m, const float* __restrict__ lng,
            const float* __restrict__ lnb, ushort* __restrict__ Ahi,
            ushort* __restrict__ Alo) {
    const int wid = threadIdx.x >> 6, lane = threadIdx.x & 63;
    const int row = (blockIdx.x << 2) + wid;
    const float4 a = ((const float4*)(m + (size_t)row * Dm))[lane];
    float s  = a.x + a.y + a.z + a.w;
    float ss = a.x*a.x + a.y*a.y + a.z*a.z + a.w*a.w;
    #pragma unroll
    for (int off = 32; off > 0; off >>= 1) {
        s  += __shfl_xor(s, off);
        ss += __shfl_xor(ss, off);
    }
    const float mu = s * (1.0f / 256.0f);
    const float rs = rsqrtf(ss * (1.0f / 256.0f) - mu * mu + 1e-5f);
    const float4 g = ((const float4*)lng)[lane];
    const float4 b = ((const float4*)lnb)[lane];
    float x0 = (a.x - mu) * rs * g.x + b.x;
    float x1 = (a.y - mu) * rs * g.y + b.y;
    float x2 = (a.z - mu) * rs * g.z + b.z;
    float x3 = (a.w - mu) * rs * g.w + b.w;
    ushort4 hi, lo;
    hi.x = f2bf(x0); lo.x = f2bf(x0 - bf2f(hi.x));
    hi.y = f2bf(x1); lo.y = f2bf(x1 - bf2f(hi.y));
    hi.z = f2bf(x2); lo.z = f2bf(x2 - bf2f(hi.z));
    hi.w = f2bf(x3); lo.w = f2bf(x3 - bf2f(hi.w));
    ((ushort4*)(Ahi + (size_t)row * Dm))[lane] = hi;
    ((ushort4*)(Alo + (size_t)row * Dm))[lane] = lo;
}

// ---------------------------------------------------------------------------
// Split the 5 weight matrices into bf16 hi/lo (stacked [5][256][256]).
// ---------------------------------------------------------------------------
__global__ __launch_bounds__(256)
void w_prep(const float* __restrict__ W0, const float* __restrict__ W1,
            const float* __restrict__ W2, const float* __restrict__ W3,
            const float* __restrict__ W4, ushort* __restrict__ Whi,
            ushort* __restrict__ Wlo) {
    const float* Ws[5] = {W0, W1, W2, W3, W4};
    const int mat = blockIdx.y;
    const size_t idx = ((size_t)blockIdx.x * 256 + threadIdx.x) * 4;
    const float4 v = *(const float4*)(Ws[mat] + idx);
    ushort4 hi, lo;
    hi.x = f2bf(v.x); lo.x = f2bf(v.x - bf2f(hi.x));
    hi.y = f2bf(v.y); lo.y = f2bf(v.y - bf2f(hi.y));
    hi.z = f2bf(v.z); lo.z = f2bf(v.z - bf2f(hi.z));
    hi.w = f2bf(v.w); lo.w = f2bf(v.w - bf2f(hi.w));
    const size_t o = (size_t)mat * 65536 + idx;
    *(ushort4*)(Whi + o) = hi;
    *(ushort4*)(Wlo + o) = lo;
}

// ---------------------------------------------------------------------------
// Mask decode (robust to int32 / float32 / byte bool encodings).
// ---------------------------------------------------------------------------
__global__ void mask_decode_kernel(const unsigned* __restrict__ seq_raw,
                                   const unsigned* __restrict__ res_raw,
                                   float* __restrict__ seqflag,
                                   float* __restrict__ kbias) {
    __shared__ unsigned long long sb[4], sf[4];
    __shared__ int enc;
    const int t = threadIdx.x;
    unsigned w = 0;
    if (t < 64)        w = seq_raw[t];
    else if (t < 128)  w = res_raw[t - 64];
    bool bad = (w != 0u) && (w != 1u) && (w != 0x3f800000u);
    bool isf = (w == 0x3f800000u);
    unsigned long long bm = __ballot(bad);
    unsigned long long fm = __ballot(isf);
    const int wid = t >> 6;
    if ((t & 63) == 0) { sb[wid] = bm; sf[wid] = fm; }
    __syncthreads();
    if (t == 0) {
        unsigned long long B = sb[0] | sb[1];
        unsigned long long F = sf[0] | sf[1];
        enc = B ? 2 : (F ? 1 : 0);
    }
    __syncthreads();
    const int e = enc;
    int sv, rv;
    if (e == 2) {
        const unsigned char* sp = (const unsigned char*)seq_raw;
        const unsigned char* rp = (const unsigned char*)res_raw;
        sv = sp[t]; rv = rp[t];
    } else if (e == 1) {
        sv = (((const float*)seq_raw)[t] != 0.0f);
        rv = (((const float*)res_raw)[t] != 0.0f);
    } else {
        sv = (seq_raw[t] != 0u);
        rv = (res_raw[t] != 0u);
    }
    seqflag[t] = sv ? 1.0f : 0.0f;
    kbias[t]   = rv ? NEG_INF : 0.0f;
}

// ---------------------------------------------------------------------------
// bf16x3 split-precision MFMA GEMM: C[m][n] = sum_k A[m][k] * W[n][k]
// A = Ahi+Alo, W = Whi+Wlo; 3 products (hi*hi, lo*hi, hi*lo).
// 128x128 tile, BK=32, global_load_lds staging, XOR-swizzled LDS.
// mode 0: out bf16 = acc*scale; mode 1: out f32 = sigmoid(acc+bias);
// mode 2: out f32 = acc+bias.
// ---------------------------------------------------------------------------
__global__ __launch_bounds__(256)
void gemm_mfma(const ushort* __restrict__ Ahi, const ushort* __restrict__ Alo,
               const ushort* __restrict__ Whi, const ushort* __restrict__ Wlo,
               const float* __restrict__ bias, void* __restrict__ outp,
               float scale, int mode) {
    __shared__ __align__(16) ushort lds[16384];  // Ahi|Alo|Whi|Wlo, 4 x 128x32
    const int tid = threadIdx.x;
    const int lane = tid & 63, wave = tid >> 6;
    const int li = lane & 15, quad = lane >> 4;
    const int m0 = blockIdx.y << 7, n0 = blockIdx.x << 7;
    const int wm = (wave >> 1) << 6, wn = (wave & 1) << 6;
    const int srow = tid >> 2, slot = tid & 3;
    const int sw0 = (srow & 3) ^ ((srow >> 2) & 3);
    const int gk0 = (slot ^ sw0) << 3;           // swizzled k-group (elements)

    f32x4 zero = {0.f, 0.f, 0.f, 0.f};
    f32x4 acc[4][4];
    #pragma unroll
    for (int i = 0; i < 4; ++i)
        #pragma unroll
        for (int j = 0; j < 4; ++j) acc[i][j] = zero;

    for (int kt = 0; kt < 256; kt += 32) {
        #pragma unroll
        for (int j = 0; j < 2; ++j) {
            const int r = j * 64 + srow;
            const size_t ao = (size_t)(m0 + r) * 256 + kt + gk0;
            const size_t wo = (size_t)(n0 + r) * 256 + kt + gk0;
            const int lo = j * 2048 + wave * 512;
            gload_lds16(Ahi + ao, &lds[lo]);
            gload_lds16(Alo + ao, &lds[4096 + lo]);
            gload_lds16(Whi + wo, &lds[8192 + lo]);
            gload_lds16(Wlo + wo, &lds[12288 + lo]);
        }
        __syncthreads();
        bf16x8 ah[4], al[4], bh[4], bl[4];
        #pragma unroll
        for (int mt = 0; mt < 4; ++mt) {
            const int r = wm + mt * 16 + li;
            const int sw = (r & 3) ^ ((r >> 2) & 3);
            const int off = r * 32 + ((quad ^ sw) << 3);
            ah[mt] = *(const bf16x8*)&lds[off];
            al[mt] = *(const bf16x8*)&lds[4096 + off];
        }
        #pragma unroll
        for (int nt = 0; nt < 4; ++nt) {
            const int r = wn + nt * 16 + li;
            const int sw = (r & 3) ^ ((r >> 2) & 3);
            const int off = r * 32 + ((quad ^ sw) << 3);
            bh[nt] = *(const bf16x8*)&lds[8192 + off];
            bl[nt] = *(const bf16x8*)&lds[12288 + off];
        }
        #pragma unroll
        for (int mt = 0; mt < 4; ++mt)
            #pragma unroll
            for (int nt = 0; nt < 4; ++nt) {
                acc[mt][nt] = mfma16(ah[mt], bh[nt], acc[mt][nt]);
                acc[mt][nt] = mfma16(al[mt], bh[nt], acc[mt][nt]);
                acc[mt][nt] = mfma16(ah[mt], bl[nt], acc[mt][nt]);
            }
        __syncthreads();
    }

    #pragma unroll
    for (int mt = 0; mt < 4; ++mt) {
        const int rowb = m0 + wm + mt * 16 + quad * 4;
        #pragma unroll
        for (int nt = 0; nt < 4; ++nt) {
            const int col = n0 + wn + nt * 16 + li;
            const float bv = (mode != 0 && bias) ? bias[col] : 0.0f;
            #pragma unroll
            for (int r = 0; r < 4; ++r) {
                const size_t o = (size_t)(rowb + r) * 256 + col;
                const float v = acc[mt][nt][r];
                if (mode == 0) {
                    ((ushort*)outp)[o] = f2bf(v * scale);
                } else if (mode == 1) {
                    const float x = v + bv;
                    ((float*)outp)[o] = 1.0f / (1.0f + __expf(-x));
                } else {
                    ((float*)outp)[o] = v + bv;
                }
            }
        }
    }
}

// ---------------------------------------------------------------------------
// MFMA attention. Block = (h, qtile of 64, s); 4 waves x 16 queries.
// K staged swizzled (global_load_lds), V transposed in LDS, P round-trips
// through LDS into A-operand layout. Epilogue gates and writes O hi/lo bf16.
// ---------------------------------------------------------------------------
__global__ __launch_bounds__(256)
void attn_mfma(const ushort* __restrict__ Qb, const ushort* __restrict__ Kb,
               const ushort* __restrict__ Vb, const float* __restrict__ Gb,
               const float* __restrict__ seqflag, const float* __restrict__ kbias,
               ushort* __restrict__ Ohi, ushort* __restrict__ Olo) {
    __shared__ __align__(16) ushort Pb[4 * 16 * 264];  // 33 KB; [0..8191] aliases K tile
    __shared__ __align__(16) ushort Vt[32 * 264];      // 16.9 KB transposed V
    const int h = blockIdx.x, qt = blockIdx.y, s = blockIdx.z;
    const int tid = threadIdx.x, lane = tid & 63, wave = tid >> 6;
    const int li = lane & 15, quad = lane >> 4;

    // K stage: 256 keys x 32 c, swizzled slots
    const int srow = tid >> 2, slot = tid & 3;
    const int sw0 = (srow & 3) ^ ((srow >> 2) & 3);
    const int gk0 = (slot ^ sw0) << 3;
    #pragma unroll
    for (int i = 0; i < 4; ++i) {
        const int r = i * 64 + srow;
        const ushort* g = Kb + ((size_t)(s * 256 + r) * 256 + h * 32 + gk0);
        gload_lds16(g, &Pb[i * 2048 + wave * 512]);
    }
    // V transpose: thread t = key t
    {
        const ushort* vrow = Vb + ((size_t)(s * 256 + tid) * 256 + h * 32);
        #pragma unroll
        for (int gb = 0; gb < 4; ++gb) {
            bf16x8 vv = *(const bf16x8*)(vrow + gb * 8);
            #pragma unroll
            for (int j = 0; j < 8; ++j)
                Vt[(gb * 8 + j) * 264 + tid] = (ushort)vv[j];
        }
    }
    // Q A-fragment (m = li, k = quad*8+j over the 32 channels)
    const int qrow = qt * 64 + wave * 16 + li;
    const bf16x8 qf = *(const bf16x8*)(Qb + ((size_t)(s * 256 + qrow) * 256 + h * 32 + quad * 8));
    float sflag[4];
    #pragma unroll
    for (int r = 0; r < 4; ++r)
        sflag[r] = seqflag[qt * 64 + wave * 16 + quad * 4 + r];

    __syncthreads();

    f32x4 zero = {0.f, 0.f, 0.f, 0.f};
    f32x4 sc[16];
    #pragma unroll
    for (int t = 0; t < 16; ++t) {
        const int kr = t * 16 + li;
        const int sw = (kr & 3) ^ ((kr >> 2) & 3);
        const bf16x8 kf = *(const bf16x8*)&Pb[kr * 32 + ((quad ^ sw) << 3)];
        sc[t] = mfma16(qf, kf, zero);
    }
    // bias + row max
    float mx[4] = {-1e30f, -1e30f, -1e30f, -1e30f};
    #pragma unroll
    for (int t = 0; t < 16; ++t) {
        const float kbt = kbias[t * 16 + li];
        #pragma unroll
        for (int r = 0; r < 4; ++r) {
            const float b = (sflag[r] != 0.0f) ? NEG_INF : kbt;
            const float x = sc[t][r] + b;
            sc[t][r] = x;
            mx[r] = fmaxf(mx[r], x);
        }
    }
    #pragma unroll
    for (int r = 0; r < 4; ++r)
        #pragma unroll
        for (int off = 1; off < 16; off <<= 1)
            mx[r] = fmaxf(mx[r], __shfl_xor(mx[r], off));
    float ls[4] = {0.f, 0.f, 0.f, 0.f};
    #pragma unroll
    for (int t = 0; t < 16; ++t)
        #pragma unroll
        for (int r = 0; r < 4; ++r) {
            const float p = __expf(sc[t][r] - mx[r]);
            sc[t][r] = p;
            ls[r] += p;
        }
    #pragma unroll
    for (int r = 0; r < 4; ++r)
        #pragma unroll
        for (int off = 1; off < 16; off <<= 1)
            ls[r] += __shfl_xor(ls[r], off);

    __syncthreads();   // all waves done reading K before P overwrites it
    ushort* Pw = &Pb[wave * 16 * 264];
    #pragma unroll
    for (int t = 0; t < 16; ++t)
        #pragma unroll
        for (int r = 0; r < 4; ++r)
            Pw[(quad * 4 + r) * 264 + t * 16 + li] = f2bf(sc[t][r]);
    __syncthreads();

    f32x4 o0 = zero, o1 = zero;
    #pragma unroll
    for (int kc = 0; kc < 8; ++kc) {
        const bf16x8 pf = *(const bf16x8*)&Pw[li * 264 + kc * 32 + quad * 8];
        const bf16x8 v0 = *(const bf16x8*)&Vt[li * 264 + kc * 32 + quad * 8];
        const bf16x8 v1 = *(const bf16x8*)&Vt[(16 + li) * 264 + kc * 32 + quad * 8];
        o0 = mfma16(pf, v0, o0);
        o1 = mfma16(pf, v1, o1);
    }
    #pragma unroll
    for (int r = 0; r < 4; ++r) {
        const float inv = 1.0f / ls[r];
        const size_t ro = (size_t)(s * 256 + qt * 64 + wave * 16 + quad * 4 + r) * 256 + h * 32;
        const float x0 = o0[r] * inv * Gb[ro + li];
        const float x1 = o1[r] * inv * Gb[ro + 16 + li];
        const ushort h0 = f2bf(x0), h1 = f2bf(x1);
        Ohi[ro + li] = h0;       Olo[ro + li] = f2bf(x0 - bf2f(h0));
        Ohi[ro + 16 + li] = h1;  Olo[ro + 16 + li] = f2bf(x1 - bf2f(h1));
    }
}

// ---------------------------------------------------------------------------
// Launch
// ---------------------------------------------------------------------------
extern "C" void kernel_launch(void* const* d_in, const int* in_sizes, int n_in,
                              void* d_out, int out_size, void* d_ws, size_t ws_size,
                              hipStream_t stream) {
    const float* m    = (const float*)d_in[0];
    const unsigned* seqp = (const unsigned*)d_in[1];
    const unsigned* resp = (const unsigned*)d_in[2];
    const float* lng  = (const float*)d_in[3];
    const float* lnb  = (const float*)d_in[4];
    const float* Wq   = (const float*)d_in[5];
    const float* Wk   = (const float*)d_in[6];
    const float* Wv   = (const float*)d_in[7];
    const float* Wg   = (const float*)d_in[8];
    const float* bg   = (const float*)d_in[9];
    const float* Wo   = (const float*)d_in[10];
    const float* bo   = (const float*)d_in[11];
    float* out = (float*)d_out;

    char* p = (char*)d_ws;
    const size_t ABYTES = (size_t)Mrows * Dm * 2;      // 16.78 MB
    ushort* Ahi = (ushort*)p; p += ABYTES;
    ushort* Alo = (ushort*)p; p += ABYTES;
    ushort* Whi = (ushort*)p; p += 5 * 65536 * 2;
    ushort* Wlo = (ushort*)p; p += 5 * 65536 * 2;
    ushort* qb  = (ushort*)p; p += ABYTES;
    ushort* kb  = (ushort*)p; p += ABYTES;
    ushort* vb  = (ushort*)p; p += ABYTES;
    float*  gbuf = (float*)p; p += (size_t)Mrows * Dm * 4;  // 33.55 MB
    ushort* Ohi = (ushort*)p; p += ABYTES;
    ushort* Olo = (ushort*)p; p += ABYTES;
    float* seqflag = (float*)p; p += 1024;
    float* kbias   = (float*)p; p += 1024;

    a_prep<<<Mrows / 4, 256, 0, stream>>>(m, lng, lnb, Ahi, Alo);
    w_prep<<<dim3(64, 5), 256, 0, stream>>>(Wq, Wk, Wv, Wg, Wo, Whi, Wlo);
    mask_decode_kernel<<<1, 256, 0, stream>>>(seqp, resp, seqflag, kbias);

    const dim3 gg(2, 256);
    const float qscale = 0.17677669529663687f;   // 1/sqrt(32)
    gemm_mfma<<<gg, 256, 0, stream>>>(Ahi, Alo, Whi + 0 * 65536, Wlo + 0 * 65536, nullptr, qb, qscale, 0);
    gemm_mfma<<<gg, 256, 0, stream>>>(Ahi, Alo, Whi + 1 * 65536, Wlo + 1 * 65536, nullptr, kb, 1.0f, 0);
    gemm_mfma<<<gg, 256, 0, stream>>>(Ahi, Alo, Whi + 2 * 65536, Wlo + 2 * 65536, nullptr, vb, 1.0f, 0);
    gemm_mfma<<<gg, 256, 0, stream>>>(Ahi, Alo, Whi + 3 * 65536, Wlo + 3 * 65536, bg, gbuf, 1.0f, 1);

    attn_mfma<<<dim3(8, 4, 128), 256, 0, stream>>>(qb, kb, vb, gbuf, seqflag, kbias, Ohi, Olo);

    gemm_mfma<<<gg, 256, 0, stream>>>(Ohi, Olo, Whi + 4 * 65536, Wlo + 4 * 65536, bo, out, 1.0f, 2);
}

// Round 5
// 264.792 us; speedup vs baseline: 2.7187x; 1.0572x over previous
//
#include <hip/hip_runtime.h>
#include <math.h>

#define NEG_INF -10000.0f

typedef short bf16x8 __attribute__((ext_vector_type(8)));
typedef float f32x4 __attribute__((ext_vector_type(4)));

static constexpr int Dm = 256;   // model dim
static constexpr int Lm = 256;   // residues
static constexpr int Sm = 128;   // sequences
static constexpr int Mrows = Sm * Lm;  // 32768

__device__ __forceinline__ ushort f2bf(float x) {
    unsigned u = __float_as_uint(x);
    unsigned r = (u + 0x7FFFu + ((u >> 16) & 1u)) >> 16;
    return (ushort)r;
}
__device__ __forceinline__ float bf2f(ushort h) {
    return __uint_as_float(((unsigned)h) << 16);
}
__device__ __forceinline__ void gload_lds16(const void* g, void* l) {
    __builtin_amdgcn_global_load_lds((__attribute__((address_space(1))) void*)g,
                                     (__attribute__((address_space(3))) void*)l,
                                     16, 0, 0);
}
__device__ __forceinline__ f32x4 mfma16(bf16x8 a, bf16x8 b, f32x4 c) {
    return __builtin_amdgcn_mfma_f32_16x16x32_bf16(a, b, c, 0, 0, 0);
}

// ---------------------------------------------------------------------------
// LayerNorm stats: one wave per row -> (mu, rsqrt(var+eps))
// ---------------------------------------------------------------------------
__global__ __launch_bounds__(256)
void ln_stats(const float* __restrict__ m, float* __restrict__ stats) {
    const int wid = threadIdx.x >> 6, lane = threadIdx.x & 63;
    const int row = (blockIdx.x << 2) + wid;
    const float4 a = ((const float4*)(m + (size_t)row * Dm))[lane];
    float s  = a.x + a.y + a.z + a.w;
    float ss = a.x*a.x + a.y*a.y + a.z*a.z + a.w*a.w;
    #pragma unroll
    for (int off = 32; off > 0; off >>= 1) {
        s  += __shfl_xor(s, off);
        ss += __shfl_xor(ss, off);
    }
    if (lane == 0) {
        const float mu = s * (1.0f / 256.0f);
        float2 st;
        st.x = mu;
        st.y = rsqrtf(ss * (1.0f / 256.0f) - mu * mu + 1e-5f);
        ((float2*)stats)[row] = st;
    }
}

// ---------------------------------------------------------------------------
// Split 5 weight matrices into bf16 hi/lo (stacked [5][256][256]).
// ---------------------------------------------------------------------------
__global__ __launch_bounds__(256)
void w_prep(const float* __restrict__ W0, const float* __restrict__ W1,
            const float* __restrict__ W2, const float* __restrict__ W3,
            const float* __restrict__ W4, ushort* __restrict__ Whi,
            ushort* __restrict__ Wlo) {
    const float* Ws[5] = {W0, W1, W2, W3, W4};
    const int mat = blockIdx.y;
    const size_t idx = ((size_t)blockIdx.x * 256 + threadIdx.x) * 4;
    const float4 v = *(const float4*)(Ws[mat] + idx);
    ushort4 hi, lo;
    hi.x = f2bf(v.x); lo.x = f2bf(v.x - bf2f(hi.x));
    hi.y = f2bf(v.y); lo.y = f2bf(v.y - bf2f(hi.y));
    hi.z = f2bf(v.z); lo.z = f2bf(v.z - bf2f(hi.z));
    hi.w = f2bf(v.w); lo.w = f2bf(v.w - bf2f(hi.w));
    const size_t o = (size_t)mat * 65536 + idx;
    *(ushort4*)(Whi + o) = hi;
    *(ushort4*)(Wlo + o) = lo;
}

// ---------------------------------------------------------------------------
// Mask decode: qflag[q] = seq_pad[q] ? NEG_INF : 0 ; kbias[k] = res_pad[k] ? NEG_INF : 0
// NOTE reference semantics: pad = (seq_pad[q] | res_pad[k]) * NEG_INF — an OR.
// For seq-padded queries the bias is UNIFORM over k (softmax-invariant), so
// the attention kernel must SELECT (ignore kbias), not add.
// ---------------------------------------------------------------------------
__global__ void mask_decode_kernel(const unsigned* __restrict__ seq_raw,
                                   const unsigned* __restrict__ res_raw,
                                   float* __restrict__ qflag,
                                   float* __restrict__ kbias) {
    __shared__ unsigned long long sb[4], sf[4];
    __shared__ int enc;
    const int t = threadIdx.x;
    unsigned w = 0;
    if (t < 64)        w = seq_raw[t];
    else if (t < 128)  w = res_raw[t - 64];
    bool bad = (w != 0u) && (w != 1u) && (w != 0x3f800000u);
    bool isf = (w == 0x3f800000u);
    unsigned long long bm = __ballot(bad);
    unsigned long long fm = __ballot(isf);
    const int wid = t >> 6;
    if ((t & 63) == 0) { sb[wid] = bm; sf[wid] = fm; }
    __syncthreads();
    if (t == 0) {
        unsigned long long B = sb[0] | sb[1];
        unsigned long long F = sf[0] | sf[1];
        enc = B ? 2 : (F ? 1 : 0);
    }
    __syncthreads();
    const int e = enc;
    int sv, rv;
    if (e == 2) {
        const unsigned char* sp = (const unsigned char*)seq_raw;
        const unsigned char* rp = (const unsigned char*)res_raw;
        sv = sp[t]; rv = rp[t];
    } else if (e == 1) {
        sv = (((const float*)seq_raw)[t] != 0.0f);
        rv = (((const float*)res_raw)[t] != 0.0f);
    } else {
        sv = (seq_raw[t] != 0u);
        rv = (res_raw[t] != 0u);
    }
    qflag[t] = sv ? NEG_INF : 0.0f;
    kbias[t] = rv ? NEG_INF : 0.0f;
}

// ---------------------------------------------------------------------------
// Fused QKVG GEMM with LN fused into A staging.
// Block tile: M=64 rows of LN(m), N=512 (= 2 weight matrices), BK=32.
// grid (2, 512). A = Ahi + Alo (split in-kernel), W = Whi only.
// Outputs bf16: q (scaled), k, v, g=sigmoid(.+bg).
// ---------------------------------------------------------------------------
__global__ __launch_bounds__(256, 2)
void qkvg_fused(const float* __restrict__ m, const float* __restrict__ stats,
                const float* __restrict__ lng, const float* __restrict__ lnb,
                const ushort* __restrict__ Whi, const float* __restrict__ bg,
                ushort* __restrict__ qb, ushort* __restrict__ kb,
                ushort* __restrict__ vb, ushort* __restrict__ gbf,
                float qscale) {
    __shared__ __align__(16) ushort Ah[64 * 32];
    __shared__ __align__(16) ushort Al[64 * 32];
    __shared__ __align__(16) ushort Wh[512 * 32];
    const int tid = threadIdx.x, lane = tid & 63, wave = tid >> 6;
    const int li = lane & 15, quad = lane >> 4;
    const int nb = blockIdx.x, m0 = blockIdx.y << 6;
    const int wm = (wave & 1) << 5;         // 0 / 32
    const int wn = (wave >> 1) << 8;        // 0 / 256
    const int mat = nb * 2 + (wave >> 1);   // which weight matrix this wave owns

    const int arow = tid >> 2, aslot = tid & 3;
    const int asw = (arow & 3) ^ ((arow >> 2) & 3);
    const float2 st = ((const float2*)stats)[m0 + arow];
    const float mu = st.x, rs = st.y;

    f32x4 zero = {0.f, 0.f, 0.f, 0.f};
    f32x4 acc[2][16];
    #pragma unroll
    for (int i = 0; i < 2; ++i)
        #pragma unroll
        for (int j = 0; j < 16; ++j) acc[i][j] = zero;

    for (int kt = 0; kt < 256; kt += 32) {
        #pragma unroll
        for (int i = 0; i < 8; ++i) {
            const int wrow = i * 64 + (tid >> 2);
            const int wsw = (wrow & 3) ^ ((wrow >> 2) & 3);
            const int g = (tid & 3) ^ wsw;
            gload_lds16(Whi + ((size_t)(nb * 512 + wrow) * 256 + kt + g * 8),
                        &Wh[i * 2048 + wave * 512]);
        }
        {
            const float* ap = m + (size_t)(m0 + arow) * 256 + kt + aslot * 8;
            const float4 v0 = *(const float4*)ap;
            const float4 v1 = *(const float4*)(ap + 4);
            const float4 g0 = *(const float4*)(lng + kt + aslot * 8);
            const float4 g1 = *(const float4*)(lng + kt + aslot * 8 + 4);
            const float4 b0 = *(const float4*)(lnb + kt + aslot * 8);
            const float4 b1 = *(const float4*)(lnb + kt + aslot * 8 + 4);
            float xs[8] = {v0.x, v0.y, v0.z, v0.w, v1.x, v1.y, v1.z, v1.w};
            float gs[8] = {g0.x, g0.y, g0.z, g0.w, g1.x, g1.y, g1.z, g1.w};
            float bs[8] = {b0.x, b0.y, b0.z, b0.w, b1.x, b1.y, b1.z, b1.w};
            bf16x8 hi8, lo8;
            #pragma unroll
            for (int e = 0; e < 8; ++e) {
                const float x = (xs[e] - mu) * rs * gs[e] + bs[e];
                const ushort h = f2bf(x);
                hi8[e] = (short)h;
                lo8[e] = (short)f2bf(x - bf2f(h));
            }
            const int adst = arow * 32 + ((aslot ^ asw) << 3);
            *(bf16x8*)&Ah[adst] = hi8;
            *(bf16x8*)&Al[adst] = lo8;
        }
        __syncthreads();
        bf16x8 ah[2], al[2];
        #pragma unroll
        for (int mt = 0; mt < 2; ++mt) {
            const int r = wm + mt * 16 + li;
            const int sw = (r & 3) ^ ((r >> 2) & 3);
            const int off = r * 32 + ((quad ^ sw) << 3);
            ah[mt] = *(const bf16x8*)&Ah[off];
            al[mt] = *(const bf16x8*)&Al[off];
        }
        #pragma unroll
        for (int nt = 0; nt < 16; ++nt) {
            const int rn = wn + nt * 16 + li;
            const int sw = (rn & 3) ^ ((rn >> 2) & 3);
            const bf16x8 bh = *(const bf16x8*)&Wh[rn * 32 + ((quad ^ sw) << 3)];
            acc[0][nt] = mfma16(ah[0], bh, acc[0][nt]);
            acc[0][nt] = mfma16(al[0], bh, acc[0][nt]);
            acc[1][nt] = mfma16(ah[1], bh, acc[1][nt]);
            acc[1][nt] = mfma16(al[1], bh, acc[1][nt]);
        }
        __syncthreads();
    }

    ushort* outp = (mat == 0) ? qb : (mat == 1) ? kb : (mat == 2) ? vb : gbf;
    #pragma unroll
    for (int mt = 0; mt < 2; ++mt) {
        #pragma unroll
        for (int nt = 0; nt < 16; ++nt) {
            const int c_in = nt * 16 + li;
            const float bgv = bg[c_in];
            #pragma unroll
            for (int r = 0; r < 4; ++r) {
                const int row = m0 + wm + mt * 16 + quad * 4 + r;
                float v = acc[mt][nt][r];
                if (mat == 0) v *= qscale;
                if (mat == 3) v = 1.0f / (1.0f + __expf(-(v + bgv)));
                outp[(size_t)row * 256 + c_in] = f2bf(v);
            }
        }
    }
}

// ---------------------------------------------------------------------------
// Attention v3. Block = (h, s); 4 waves x 64 queries (4 chunks of 16).
// KEY TRICK: the S^T MFMA's A-operand (K rows) is PERMUTED so that the
// resulting C/D layout is already the PV A-operand layout:
//   tile t, row m  ->  key (t>>1)*32 + 8*(m>>2) + 4*(t&1) + (m&3)
// Lane (li,quad) then holds S^T[key=32*kbk+8*quad+{0..3}] in sc[2kbk] and
// [.. +4..7] in sc[2kbk+1] -> pf built per-lane, ZERO cross-lane moves.
// Mask semantics (reference is an OR): seq-padded query -> bias uniform over
// keys -> softmax-invariant -> SELECT kmul=0 (ignore kbias), never add both.
// ---------------------------------------------------------------------------
__global__ __launch_bounds__(256, 2)
void attn2(const ushort* __restrict__ Qb, const ushort* __restrict__ Kb,
           const ushort* __restrict__ Vb, const ushort* __restrict__ Gb,
           const float* __restrict__ qflag, const float* __restrict__ kbias,
           ushort* __restrict__ Ohi, ushort* __restrict__ Olo) {
    __shared__ __align__(16) ushort Kl[256 * 32];   // 16 KB, swizzled rows
    __shared__ __align__(16) ushort Vt[16 * 1024];  // 32 KB, chunk layout
    const int h = blockIdx.x, s = blockIdx.y;
    const int tid = threadIdx.x, lane = tid & 63, wave = tid >> 6;
    const int li = lane & 15, quad = lane >> 4;

    // --- K staging: 256 keys x 32 ch, gemm-style XOR swizzle ---
    const int srow = tid >> 2, slot = tid & 3;
    const int sw0 = (srow & 3) ^ ((srow >> 2) & 3);
    const int gk0 = (slot ^ sw0) << 3;
    #pragma unroll
    for (int i = 0; i < 4; ++i) {
        const int r = i * 64 + srow;
        gload_lds16(Kb + ((size_t)(s * 256 + r) * 256 + h * 32 + gk0),
                    &Kl[i * 2048 + wave * 512]);
    }
    // --- V transpose: thread = key. Chunk layout:
    // Vt[kb*2048 + ct*1024 + vq*128 + ((cl^((4*kb+vq)&7))<<3) + vj]
    //   = V[key=32kb+8vq+vj][c=16ct+cl]
    {
        const ushort* vrow = Vb + ((size_t)(s * 256 + tid) * 256 + h * 32);
        bf16x8 vv0 = *(const bf16x8*)(vrow);
        bf16x8 vv1 = *(const bf16x8*)(vrow + 8);
        bf16x8 vv2 = *(const bf16x8*)(vrow + 16);
        bf16x8 vv3 = *(const bf16x8*)(vrow + 24);
        const int vkb = tid >> 5, vq = (tid >> 3) & 3, vj = tid & 7;
        const int vsw = (4 * vkb + vq) & 7;
        const int vbase = vkb * 2048 + vq * 128 + vj;
        #pragma unroll
        for (int c = 0; c < 32; ++c) {
            const short val = (c < 8) ? vv0[c & 7] : (c < 16) ? vv1[c & 7]
                            : (c < 24) ? vv2[c & 7] : vv3[c & 7];
            const int ct = c >> 4, cl = c & 15;
            Vt[vbase + ct * 1024 + ((cl ^ vsw) << 3)] = (ushort)val;
        }
    }
    __syncthreads();

    f32x4 zero = {0.f, 0.f, 0.f, 0.f};

    for (int chunk = 0; chunk < 4; ++chunk) {
        const int q0 = wave * 64 + chunk * 16;     // query base (residue)
        // Q B-frag: B[n=li][k=quad*8+j]
        const bf16x8 qf = *(const bf16x8*)(Qb + ((size_t)(s * 256 + q0 + li) * 256 + h * 32 + quad * 8));
        // OR-mask select: seq-padded query -> ignore kbias entirely.
        const float kmul = (qflag[q0 + li] != 0.0f) ? 0.0f : 1.0f;

        // S^T tiles with permuted K rows (see header comment).
        f32x4 sc[16];
        #pragma unroll
        for (int t = 0; t < 16; ++t) {
            const int kr = (t >> 1) * 32 + ((li >> 2) << 3) + ((t & 1) << 2) + (li & 3);
            const int sw = (kr & 3) ^ ((kr >> 2) & 3);
            const bf16x8 kf = *(const bf16x8*)&Kl[kr * 32 + ((quad ^ sw) << 3)];
            sc[t] = mfma16(kf, qf, zero);
        }
        // sc[t][r] = S^T[key = (t>>1)*32 + 8*quad + 4*(t&1) + r][query = li]
        float mx = -1e30f;
        #pragma unroll
        for (int t = 0; t < 16; ++t) {
            const float4 kb4 = ((const float4*)kbias)[(t >> 1) * 8 + quad * 2 + (t & 1)];
            sc[t][0] += kmul * kb4.x;  sc[t][1] += kmul * kb4.y;
            sc[t][2] += kmul * kb4.z;  sc[t][3] += kmul * kb4.w;
            mx = fmaxf(mx, fmaxf(fmaxf(sc[t][0], sc[t][1]), fmaxf(sc[t][2], sc[t][3])));
        }
        mx = fmaxf(mx, __shfl_xor(mx, 16));
        mx = fmaxf(mx, __shfl_xor(mx, 32));
        float ls = 0.0f;
        #pragma unroll
        for (int t = 0; t < 16; ++t) {
            #pragma unroll
            for (int r = 0; r < 4; ++r) {
                const float p = __expf(sc[t][r] - mx);
                sc[t][r] = p;
                ls += p;
            }
        }
        ls += __shfl_xor(ls, 16);
        ls += __shfl_xor(ls, 32);

        // PV: pf comes straight from this lane's sc — no shuffles.
        f32x4 a0 = zero, a1 = zero;
        #pragma unroll
        for (int kbk = 0; kbk < 8; ++kbk) {
            bf16x8 pf;
            pf[0] = (short)f2bf(sc[2 * kbk][0]);
            pf[1] = (short)f2bf(sc[2 * kbk][1]);
            pf[2] = (short)f2bf(sc[2 * kbk][2]);
            pf[3] = (short)f2bf(sc[2 * kbk][3]);
            pf[4] = (short)f2bf(sc[2 * kbk + 1][0]);
            pf[5] = (short)f2bf(sc[2 * kbk + 1][1]);
            pf[6] = (short)f2bf(sc[2 * kbk + 1][2]);
            pf[7] = (short)f2bf(sc[2 * kbk + 1][3]);
            const int vsw = (4 * kbk + quad) & 7;
            const bf16x8 v0 = *(const bf16x8*)&Vt[kbk * 2048 + quad * 128 + ((li ^ vsw) << 3)];
            const bf16x8 v1 = *(const bf16x8*)&Vt[kbk * 2048 + 1024 + quad * 128 + ((li ^ vsw) << 3)];
            a0 = mfma16(pf, v0, a0);
            a1 = mfma16(pf, v1, a1);
        }
        // epilogue: O[q=4quad+r][c=16ct+li], gate, split hi/lo
        #pragma unroll
        for (int r = 0; r < 4; ++r) {
            const float lsr = __shfl(ls, 4 * quad + r);
            const float inv = 1.0f / lsr;
            const int rowq = q0 + 4 * quad + r;
            const size_t base = (size_t)(s * 256 + rowq) * 256 + h * 32;
            const float g0 = bf2f(Gb[base + li]);
            const float g1 = bf2f(Gb[base + 16 + li]);
            const float x0 = a0[r] * inv * g0;
            const float x1 = a1[r] * inv * g1;
            const ushort h0 = f2bf(x0), h1 = f2bf(x1);
            Ohi[base + li] = h0;        Olo[base + li] = f2bf(x0 - bf2f(h0));
            Ohi[base + 16 + li] = h1;   Olo[base + 16 + li] = f2bf(x1 - bf2f(h1));
        }
    }
}

// ---------------------------------------------------------------------------
// Final GEMM (round-2 proven): out = (Ohi+Olo) @ (Whi+Wlo)^T + bias, fp32 out.
// ---------------------------------------------------------------------------
__global__ __launch_bounds__(256)
void gemm_mfma(const ushort* __restrict__ Ahi, const ushort* __restrict__ Alo,
               const ushort* __restrict__ Whi, const ushort* __restrict__ Wlo,
               const float* __restrict__ bias, void* __restrict__ outp,
               float scale, int mode) {
    __shared__ __align__(16) ushort lds[16384];
    const int tid = threadIdx.x;
    const int lane = tid & 63, wave = tid >> 6;
    const int li = lane & 15, quad = lane >> 4;
    const int m0 = blockIdx.y << 7, n0 = blockIdx.x << 7;
    const int wm = (wave >> 1) << 6, wn = (wave & 1) << 6;
    const int srow = tid >> 2, slot = tid & 3;
    const int sw0 = (srow & 3) ^ ((srow >> 2) & 3);
    const int gk0 = (slot ^ sw0) << 3;

    f32x4 zero = {0.f, 0.f, 0.f, 0.f};
    f32x4 acc[4][4];
    #pragma unroll
    for (int i = 0; i < 4; ++i)
        #pragma unroll
        for (int j = 0; j < 4; ++j) acc[i][j] = zero;

    for (int kt = 0; kt < 256; kt += 32) {
        #pragma unroll
        for (int j = 0; j < 2; ++j) {
            const int r = j * 64 + srow;
            const size_t ao = (size_t)(m0 + r) * 256 + kt + gk0;
            const size_t wo = (size_t)(n0 + r) * 256 + kt + gk0;
            const int lo = j * 2048 + wave * 512;
            gload_lds16(Ahi + ao, &lds[lo]);
            gload_lds16(Alo + ao, &lds[4096 + lo]);
            gload_lds16(Whi + wo, &lds[8192 + lo]);
            gload_lds16(Wlo + wo, &lds[12288 + lo]);
        }
        __syncthreads();
        bf16x8 ah[4], al[4], bh[4], bl[4];
        #pragma unroll
        for (int mt = 0; mt < 4; ++mt) {
            const int r = wm + mt * 16 + li;
            const int sw = (r & 3) ^ ((r >> 2) & 3);
            const int off = r * 32 + ((quad ^ sw) << 3);
            ah[mt] = *(const bf16x8*)&lds[off];
            al[mt] = *(const bf16x8*)&lds[4096 + off];
        }
        #pragma unroll
        for (int nt = 0; nt < 4; ++nt) {
            const int r = wn + nt * 16 + li;
            const int sw = (r & 3) ^ ((r >> 2) & 3);
            const int off = r * 32 + ((quad ^ sw) << 3);
            bh[nt] = *(const bf16x8*)&lds[8192 + off];
            bl[nt] = *(const bf16x8*)&lds[12288 + off];
        }
        #pragma unroll
        for (int mt = 0; mt < 4; ++mt)
            #pragma unroll
            for (int nt = 0; nt < 4; ++nt) {
                acc[mt][nt] = mfma16(ah[mt], bh[nt], acc[mt][nt]);
                acc[mt][nt] = mfma16(al[mt], bh[nt], acc[mt][nt]);
                acc[mt][nt] = mfma16(ah[mt], bl[nt], acc[mt][nt]);
            }
        __syncthreads();
    }

    #pragma unroll
    for (int mt = 0; mt < 4; ++mt) {
        const int rowb = m0 + wm + mt * 16 + quad * 4;
        #pragma unroll
        for (int nt = 0; nt < 4; ++nt) {
            const int col = n0 + wn + nt * 16 + li;
            const float bv = (mode != 0 && bias) ? bias[col] : 0.0f;
            #pragma unroll
            for (int r = 0; r < 4; ++r) {
                const size_t o = (size_t)(rowb + r) * 256 + col;
                const float v = acc[mt][nt][r];
                if (mode == 0) {
                    ((ushort*)outp)[o] = f2bf(v * scale);
                } else if (mode == 1) {
                    const float x = v + bv;
                    ((float*)outp)[o] = 1.0f / (1.0f + __expf(-x));
                } else {
                    ((float*)outp)[o] = v + bv;
                }
            }
        }
    }
}

// ---------------------------------------------------------------------------
// Launch
// ---------------------------------------------------------------------------
extern "C" void kernel_launch(void* const* d_in, const int* in_sizes, int n_in,
                              void* d_out, int out_size, void* d_ws, size_t ws_size,
                              hipStream_t stream) {
    const float* m    = (const float*)d_in[0];
    const unsigned* seqp = (const unsigned*)d_in[1];
    const unsigned* resp = (const unsigned*)d_in[2];
    const float* lng  = (const float*)d_in[3];
    const float* lnb  = (const float*)d_in[4];
    const float* Wq   = (const float*)d_in[5];
    const float* Wk   = (const float*)d_in[6];
    const float* Wv   = (const float*)d_in[7];
    const float* Wg   = (const float*)d_in[8];
    const float* bg   = (const float*)d_in[9];
    const float* Wo   = (const float*)d_in[10];
    const float* bo   = (const float*)d_in[11];
    float* out = (float*)d_out;

    char* p = (char*)d_ws;
    const size_t ABYTES = (size_t)Mrows * Dm * 2;      // 16.78 MB
    float* stats = (float*)p;  p += (size_t)Mrows * 2 * 4;
    ushort* Whi = (ushort*)p;  p += 5 * 65536 * 2;
    ushort* Wlo = (ushort*)p;  p += 5 * 65536 * 2;
    ushort* qb  = (ushort*)p;  p += ABYTES;
    ushort* kb  = (ushort*)p;  p += ABYTES;
    ushort* vb  = (ushort*)p;  p += ABYTES;
    ushort* gbf = (ushort*)p;  p += ABYTES;
    ushort* Ohi = (ushort*)p;  p += ABYTES;
    ushort* Olo = (ushort*)p;  p += ABYTES;
    float* qflag = (float*)p;  p += 1024;
    float* kbias = (float*)p;  p += 1024;

    ln_stats<<<Mrows / 4, 256, 0, stream>>>(m, stats);
    w_prep<<<dim3(64, 5), 256, 0, stream>>>(Wq, Wk, Wv, Wg, Wo, Whi, Wlo);
    mask_decode_kernel<<<1, 256, 0, stream>>>(seqp, resp, qflag, kbias);

    const float qscale = 0.17677669529663687f;   // 1/sqrt(32)
    qkvg_fused<<<dim3(2, 512), 256, 0, stream>>>(m, stats, lng, lnb, Whi, bg,
                                                 qb, kb, vb, gbf, qscale);

    attn2<<<dim3(8, 128), 256, 0, stream>>>(qb, kb, vb, gbf, qflag, kbias, Ohi, Olo);

    gemm_mfma<<<dim3(2, 256), 256, 0, stream>>>(Ohi, Olo, Whi + 4 * 65536, Wlo + 4 * 65536,
                                                bo, out, 1.0f, 2);
}

// Round 6
// 254.719 us; speedup vs baseline: 2.8263x; 1.0395x over previous
//
#include <hip/hip_runtime.h>
#include <math.h>

#define NEG_INF -10000.0f

typedef short bf16x8 __attribute__((ext_vector_type(8)));
typedef float f32x4 __attribute__((ext_vector_type(4)));

static constexpr int Dm = 256;   // model dim
static constexpr int Lm = 256;   // residues
static constexpr int Sm = 128;   // sequences
static constexpr int Mrows = Sm * Lm;  // 32768
static constexpr size_t HB = (size_t)Mrows * 32;  // head-plane stride (elems)

__device__ __forceinline__ ushort f2bf(float x) {
    unsigned u = __float_as_uint(x);
    unsigned r = (u + 0x7FFFu + ((u >> 16) & 1u)) >> 16;
    return (ushort)r;
}
__device__ __forceinline__ float bf2f(ushort h) {
    return __uint_as_float(((unsigned)h) << 16);
}
__device__ __forceinline__ void gload_lds16(const void* g, void* l) {
    __builtin_amdgcn_global_load_lds((__attribute__((address_space(1))) void*)g,
                                     (__attribute__((address_space(3))) void*)l,
                                     16, 0, 0);
}
__device__ __forceinline__ f32x4 mfma16(bf16x8 a, bf16x8 b, f32x4 c) {
    return __builtin_amdgcn_mfma_f32_16x16x32_bf16(a, b, c, 0, 0, 0);
}

// ---------------------------------------------------------------------------
// LayerNorm stats: one wave per row -> (mu, rsqrt(var+eps))
// ---------------------------------------------------------------------------
__global__ __launch_bounds__(256)
void ln_stats(const float* __restrict__ m, float* __restrict__ stats) {
    const int wid = threadIdx.x >> 6, lane = threadIdx.x & 63;
    const int row = (blockIdx.x << 2) + wid;
    const float4 a = ((const float4*)(m + (size_t)row * Dm))[lane];
    float s  = a.x + a.y + a.z + a.w;
    float ss = a.x*a.x + a.y*a.y + a.z*a.z + a.w*a.w;
    #pragma unroll
    for (int off = 32; off > 0; off >>= 1) {
        s  += __shfl_xor(s, off);
        ss += __shfl_xor(ss, off);
    }
    if (lane == 0) {
        const float mu = s * (1.0f / 256.0f);
        float2 st;
        st.x = mu;
        st.y = rsqrtf(ss * (1.0f / 256.0f) - mu * mu + 1e-5f);
        ((float2*)stats)[row] = st;
    }
}

// ---------------------------------------------------------------------------
// Split 5 weight matrices into bf16 hi/lo (stacked [5][256][256]).
// ---------------------------------------------------------------------------
__global__ __launch_bounds__(256)
void w_prep(const float* __restrict__ W0, const float* __restrict__ W1,
            const float* __restrict__ W2, const float* __restrict__ W3,
            const float* __restrict__ W4, ushort* __restrict__ Whi,
            ushort* __restrict__ Wlo) {
    const float* Ws[5] = {W0, W1, W2, W3, W4};
    const int mat = blockIdx.y;
    const size_t idx = ((size_t)blockIdx.x * 256 + threadIdx.x) * 4;
    const float4 v = *(const float4*)(Ws[mat] + idx);
    ushort4 hi, lo;
    hi.x = f2bf(v.x); lo.x = f2bf(v.x - bf2f(hi.x));
    hi.y = f2bf(v.y); lo.y = f2bf(v.y - bf2f(hi.y));
    hi.z = f2bf(v.z); lo.z = f2bf(v.z - bf2f(hi.z));
    hi.w = f2bf(v.w); lo.w = f2bf(v.w - bf2f(hi.w));
    const size_t o = (size_t)mat * 65536 + idx;
    *(ushort4*)(Whi + o) = hi;
    *(ushort4*)(Wlo + o) = lo;
}

// ---------------------------------------------------------------------------
// Mask decode: qflag[q] = seq_pad[q] ? NEG_INF : 0 ; kbias[k] = res_pad[k] ? NEG_INF : 0
// Reference semantics: pad = (seq_pad[q] | res_pad[k]) * NEG_INF — an OR.
// Seq-padded query -> uniform bias -> softmax-invariant -> SELECT, not add.
// ---------------------------------------------------------------------------
__global__ void mask_decode_kernel(const unsigned* __restrict__ seq_raw,
                                   const unsigned* __restrict__ res_raw,
                                   float* __restrict__ qflag,
                                   float* __restrict__ kbias) {
    __shared__ unsigned long long sb[4], sf[4];
    __shared__ int enc;
    const int t = threadIdx.x;
    unsigned w = 0;
    if (t < 64)        w = seq_raw[t];
    else if (t < 128)  w = res_raw[t - 64];
    bool bad = (w != 0u) && (w != 1u) && (w != 0x3f800000u);
    bool isf = (w == 0x3f800000u);
    unsigned long long bm = __ballot(bad);
    unsigned long long fm = __ballot(isf);
    const int wid = t >> 6;
    if ((t & 63) == 0) { sb[wid] = bm; sf[wid] = fm; }
    __syncthreads();
    if (t == 0) {
        unsigned long long B = sb[0] | sb[1];
        unsigned long long F = sf[0] | sf[1];
        enc = B ? 2 : (F ? 1 : 0);
    }
    __syncthreads();
    const int e = enc;
    int sv, rv;
    if (e == 2) {
        const unsigned char* sp = (const unsigned char*)seq_raw;
        const unsigned char* rp = (const unsigned char*)res_raw;
        sv = sp[t]; rv = rp[t];
    } else if (e == 1) {
        sv = (((const float*)seq_raw)[t] != 0.0f);
        rv = (((const float*)res_raw)[t] != 0.0f);
    } else {
        sv = (seq_raw[t] != 0u);
        rv = (res_raw[t] != 0u);
    }
    qflag[t] = sv ? NEG_INF : 0.0f;
    kbias[t] = rv ? NEG_INF : 0.0f;
}

// ---------------------------------------------------------------------------
// Fused QKVG GEMM with LN fused into A staging.
// Block tile: M=64, N=512 (2 matrices), BK=32. grid (2, 512).
// OUTPUT LAYOUT: head-major [8][Mrows][32] per matrix (plane stride HB).
// ---------------------------------------------------------------------------
__global__ __launch_bounds__(256, 2)
void qkvg_fused(const float* __restrict__ m, const float* __restrict__ stats,
                const float* __restrict__ lng, const float* __restrict__ lnb,
                const ushort* __restrict__ Whi, const float* __restrict__ bg,
                ushort* __restrict__ qb, ushort* __restrict__ kb,
                ushort* __restrict__ vb, ushort* __restrict__ gbf,
                float qscale) {
    __shared__ __align__(16) ushort Ah[64 * 32];
    __shared__ __align__(16) ushort Al[64 * 32];
    __shared__ __align__(16) ushort Wh[512 * 32];
    const int tid = threadIdx.x, lane = tid & 63, wave = tid >> 6;
    const int li = lane & 15, quad = lane >> 4;
    const int nb = blockIdx.x, m0 = blockIdx.y << 6;
    const int wm = (wave & 1) << 5;         // 0 / 32
    const int wn = (wave >> 1) << 8;        // 0 / 256
    const int mat = nb * 2 + (wave >> 1);   // which weight matrix this wave owns

    const int arow = tid >> 2, aslot = tid & 3;
    const int asw = (arow & 3) ^ ((arow >> 2) & 3);
    const float2 st = ((const float2*)stats)[m0 + arow];
    const float mu = st.x, rs = st.y;

    f32x4 zero = {0.f, 0.f, 0.f, 0.f};
    f32x4 acc[2][16];
    #pragma unroll
    for (int i = 0; i < 2; ++i)
        #pragma unroll
        for (int j = 0; j < 16; ++j) acc[i][j] = zero;

    for (int kt = 0; kt < 256; kt += 32) {
        #pragma unroll
        for (int i = 0; i < 8; ++i) {
            const int wrow = i * 64 + (tid >> 2);
            const int wsw = (wrow & 3) ^ ((wrow >> 2) & 3);
            const int g = (tid & 3) ^ wsw;
            gload_lds16(Whi + ((size_t)(nb * 512 + wrow) * 256 + kt + g * 8),
                        &Wh[i * 2048 + wave * 512]);
        }
        {
            const float* ap = m + (size_t)(m0 + arow) * 256 + kt + aslot * 8;
            const float4 v0 = *(const float4*)ap;
            const float4 v1 = *(const float4*)(ap + 4);
            const float4 g0 = *(const float4*)(lng + kt + aslot * 8);
            const float4 g1 = *(const float4*)(lng + kt + aslot * 8 + 4);
            const float4 b0 = *(const float4*)(lnb + kt + aslot * 8);
            const float4 b1 = *(const float4*)(lnb + kt + aslot * 8 + 4);
            float xs[8] = {v0.x, v0.y, v0.z, v0.w, v1.x, v1.y, v1.z, v1.w};
            float gs[8] = {g0.x, g0.y, g0.z, g0.w, g1.x, g1.y, g1.z, g1.w};
            float bs[8] = {b0.x, b0.y, b0.z, b0.w, b1.x, b1.y, b1.z, b1.w};
            bf16x8 hi8, lo8;
            #pragma unroll
            for (int e = 0; e < 8; ++e) {
                const float x = (xs[e] - mu) * rs * gs[e] + bs[e];
                const ushort h = f2bf(x);
                hi8[e] = (short)h;
                lo8[e] = (short)f2bf(x - bf2f(h));
            }
            const int adst = arow * 32 + ((aslot ^ asw) << 3);
            *(bf16x8*)&Ah[adst] = hi8;
            *(bf16x8*)&Al[adst] = lo8;
        }
        __syncthreads();
        bf16x8 ah[2], al[2];
        #pragma unroll
        for (int mt = 0; mt < 2; ++mt) {
            const int r = wm + mt * 16 + li;
            const int sw = (r & 3) ^ ((r >> 2) & 3);
            const int off = r * 32 + ((quad ^ sw) << 3);
            ah[mt] = *(const bf16x8*)&Ah[off];
            al[mt] = *(const bf16x8*)&Al[off];
        }
        #pragma unroll
        for (int nt = 0; nt < 16; ++nt) {
            const int rn = wn + nt * 16 + li;
            const int sw = (rn & 3) ^ ((rn >> 2) & 3);
            const bf16x8 bh = *(const bf16x8*)&Wh[rn * 32 + ((quad ^ sw) << 3)];
            acc[0][nt] = mfma16(ah[0], bh, acc[0][nt]);
            acc[0][nt] = mfma16(al[0], bh, acc[0][nt]);
            acc[1][nt] = mfma16(ah[1], bh, acc[1][nt]);
            acc[1][nt] = mfma16(al[1], bh, acc[1][nt]);
        }
        __syncthreads();
    }

    ushort* outp = (mat == 0) ? qb : (mat == 1) ? kb : (mat == 2) ? vb : gbf;
    #pragma unroll
    for (int mt = 0; mt < 2; ++mt) {
        #pragma unroll
        for (int nt = 0; nt < 16; ++nt) {
            const int c_in = nt * 16 + li;       // col within matrix (0..255)
            const int hh = c_in >> 5, ch = c_in & 31;
            const float bgv = bg[c_in];
            #pragma unroll
            for (int r = 0; r < 4; ++r) {
                const int row = m0 + wm + mt * 16 + quad * 4 + r;
                float v = acc[mt][nt][r];
                if (mat == 0) v *= qscale;
                if (mat == 3) v = 1.0f / (1.0f + __expf(-(v + bgv)));
                outp[(size_t)hh * HB + (size_t)row * 32 + ch] = f2bf(v);
            }
        }
    }
}

// ---------------------------------------------------------------------------
// Attention v4: head-major I/O. Block = (h, s): base = h*HB + s*8192.
// All reads/writes for a block are CONTIGUOUS 16 KB planes (no cross-head
// cacheline sharing). S^T K-row permutation puts scores directly in PV
// A-operand layout (zero cross-lane moves). OR-mask select semantics.
// ---------------------------------------------------------------------------
__global__ __launch_bounds__(256, 2)
void attn2(const ushort* __restrict__ Qb, const ushort* __restrict__ Kb,
           const ushort* __restrict__ Vb, const ushort* __restrict__ Gb,
           const float* __restrict__ qflag, const float* __restrict__ kbias,
           ushort* __restrict__ Ohi, ushort* __restrict__ Olo) {
    __shared__ __align__(16) ushort Kl[256 * 32];   // 16 KB, swizzled rows
    __shared__ __align__(16) ushort Vt[16 * 1024];  // 32 KB, chunk layout
    const int h = blockIdx.x, s = blockIdx.y;
    const int tid = threadIdx.x, lane = tid & 63, wave = tid >> 6;
    const int li = lane & 15, quad = lane >> 4;
    const size_t base = (size_t)h * HB + (size_t)s * 8192;

    // --- K staging: 256 keys x 32 ch, gemm-style XOR swizzle ---
    const int srow = tid >> 2, slot = tid & 3;
    const int sw0 = (srow & 3) ^ ((srow >> 2) & 3);
    const int gk0 = (slot ^ sw0) << 3;
    #pragma unroll
    for (int i = 0; i < 4; ++i) {
        const int r = i * 64 + srow;
        gload_lds16(Kb + base + (size_t)r * 32 + gk0,
                    &Kl[i * 2048 + wave * 512]);
    }
    // --- V transpose: thread = key. Chunk layout:
    // Vt[kb*2048 + ct*1024 + vq*128 + ((cl^((4*kb+vq)&7))<<3) + vj]
    //   = V[key=32kb+8vq+vj][c=16ct+cl]
    {
        const ushort* vrow = Vb + base + (size_t)tid * 32;
        bf16x8 vv0 = *(const bf16x8*)(vrow);
        bf16x8 vv1 = *(const bf16x8*)(vrow + 8);
        bf16x8 vv2 = *(const bf16x8*)(vrow + 16);
        bf16x8 vv3 = *(const bf16x8*)(vrow + 24);
        const int vkb = tid >> 5, vq = (tid >> 3) & 3, vj = tid & 7;
        const int vsw = (4 * vkb + vq) & 7;
        const int vbase = vkb * 2048 + vq * 128 + vj;
        #pragma unroll
        for (int c = 0; c < 32; ++c) {
            const short val = (c < 8) ? vv0[c & 7] : (c < 16) ? vv1[c & 7]
                            : (c < 24) ? vv2[c & 7] : vv3[c & 7];
            const int ct = c >> 4, cl = c & 15;
            Vt[vbase + ct * 1024 + ((cl ^ vsw) << 3)] = (ushort)val;
        }
    }
    __syncthreads();

    f32x4 zero = {0.f, 0.f, 0.f, 0.f};

    for (int chunk = 0; chunk < 4; ++chunk) {
        const int q0 = wave * 64 + chunk * 16;     // query base (residue)
        // Q B-frag: B[n=li][k=quad*8+j]
        const bf16x8 qf = *(const bf16x8*)(Qb + base + (size_t)(q0 + li) * 32 + quad * 8);
        // OR-mask select: seq-padded query -> ignore kbias entirely.
        const float kmul = (qflag[q0 + li] != 0.0f) ? 0.0f : 1.0f;

        // S^T tiles with permuted K rows (C/D layout == PV A-layout).
        f32x4 sc[16];
        #pragma unroll
        for (int t = 0; t < 16; ++t) {
            const int kr = (t >> 1) * 32 + ((li >> 2) << 3) + ((t & 1) << 2) + (li & 3);
            const int sw = (kr & 3) ^ ((kr >> 2) & 3);
            const bf16x8 kf = *(const bf16x8*)&Kl[kr * 32 + ((quad ^ sw) << 3)];
            sc[t] = mfma16(kf, qf, zero);
        }
        // sc[t][r] = S^T[key = (t>>1)*32 + 8*quad + 4*(t&1) + r][query = li]
        float mx = -1e30f;
        #pragma unroll
        for (int t = 0; t < 16; ++t) {
            const float4 kb4 = ((const float4*)kbias)[(t >> 1) * 8 + quad * 2 + (t & 1)];
            sc[t][0] += kmul * kb4.x;  sc[t][1] += kmul * kb4.y;
            sc[t][2] += kmul * kb4.z;  sc[t][3] += kmul * kb4.w;
            mx = fmaxf(mx, fmaxf(fmaxf(sc[t][0], sc[t][1]), fmaxf(sc[t][2], sc[t][3])));
        }
        mx = fmaxf(mx, __shfl_xor(mx, 16));
        mx = fmaxf(mx, __shfl_xor(mx, 32));
        float ls = 0.0f;
        #pragma unroll
        for (int t = 0; t < 16; ++t) {
            #pragma unroll
            for (int r = 0; r < 4; ++r) {
                const float p = __expf(sc[t][r] - mx);
                sc[t][r] = p;
                ls += p;
            }
        }
        ls += __shfl_xor(ls, 16);
        ls += __shfl_xor(ls, 32);

        // PV: pf comes straight from this lane's sc — no shuffles.
        f32x4 a0 = zero, a1 = zero;
        #pragma unroll
        for (int kbk = 0; kbk < 8; ++kbk) {
            bf16x8 pf;
            pf[0] = (short)f2bf(sc[2 * kbk][0]);
            pf[1] = (short)f2bf(sc[2 * kbk][1]);
            pf[2] = (short)f2bf(sc[2 * kbk][2]);
            pf[3] = (short)f2bf(sc[2 * kbk][3]);
            pf[4] = (short)f2bf(sc[2 * kbk + 1][0]);
            pf[5] = (short)f2bf(sc[2 * kbk + 1][1]);
            pf[6] = (short)f2bf(sc[2 * kbk + 1][2]);
            pf[7] = (short)f2bf(sc[2 * kbk + 1][3]);
            const int vsw = (4 * kbk + quad) & 7;
            const bf16x8 v0 = *(const bf16x8*)&Vt[kbk * 2048 + quad * 128 + ((li ^ vsw) << 3)];
            const bf16x8 v1 = *(const bf16x8*)&Vt[kbk * 2048 + 1024 + quad * 128 + ((li ^ vsw) << 3)];
            a0 = mfma16(pf, v0, a0);
            a1 = mfma16(pf, v1, a1);
        }
        // epilogue: O[q=4quad+r][c=16ct+li], gate, split hi/lo
        #pragma unroll
        for (int r = 0; r < 4; ++r) {
            const float lsr = __shfl(ls, 4 * quad + r);
            const float inv = 1.0f / lsr;
            const int rowq = q0 + 4 * quad + r;
            const size_t ro = base + (size_t)rowq * 32;
            const float g0 = bf2f(Gb[ro + li]);
            const float g1 = bf2f(Gb[ro + 16 + li]);
            const float x0 = a0[r] * inv * g0;
            const float x1 = a1[r] * inv * g1;
            const ushort h0 = f2bf(x0), h1 = f2bf(x1);
            Ohi[ro + li] = h0;        Olo[ro + li] = f2bf(x0 - bf2f(h0));
            Ohi[ro + 16 + li] = h1;   Olo[ro + 16 + li] = f2bf(x1 - bf2f(h1));
        }
    }
}

// ---------------------------------------------------------------------------
// Final GEMM: out = (Ohi+Olo) @ (Whi+Wlo)^T + bias, fp32 out.
// A (Ohi/Olo) is HEAD-MAJOR [8][Mrows][32]; k = head*32 + ch.
// ---------------------------------------------------------------------------
__global__ __launch_bounds__(256)
void gemm_mfma(const ushort* __restrict__ Ahi, const ushort* __restrict__ Alo,
               const ushort* __restrict__ Whi, const ushort* __restrict__ Wlo,
               const float* __restrict__ bias, void* __restrict__ outp,
               float scale, int mode) {
    __shared__ __align__(16) ushort lds[16384];
    const int tid = threadIdx.x;
    const int lane = tid & 63, wave = tid >> 6;
    const int li = lane & 15, quad = lane >> 4;
    const int m0 = blockIdx.y << 7, n0 = blockIdx.x << 7;
    const int wm = (wave >> 1) << 6, wn = (wave & 1) << 6;
    const int srow = tid >> 2, slot = tid & 3;
    const int sw0 = (srow & 3) ^ ((srow >> 2) & 3);
    const int gk0 = (slot ^ sw0) << 3;

    f32x4 zero = {0.f, 0.f, 0.f, 0.f};
    f32x4 acc[4][4];
    #pragma unroll
    for (int i = 0; i < 4; ++i)
        #pragma unroll
        for (int j = 0; j < 4; ++j) acc[i][j] = zero;

    for (int kt = 0; kt < 256; kt += 32) {
        const size_t hplane = (size_t)(kt >> 5) * HB;
        #pragma unroll
        for (int j = 0; j < 2; ++j) {
            const int r = j * 64 + srow;
            const size_t ao = hplane + (size_t)(m0 + r) * 32 + gk0;
            const size_t wo = (size_t)(n0 + r) * 256 + kt + gk0;
            const int lo = j * 2048 + wave * 512;
            gload_lds16(Ahi + ao, &lds[lo]);
            gload_lds16(Alo + ao, &lds[4096 + lo]);
            gload_lds16(Whi + wo, &lds[8192 + lo]);
            gload_lds16(Wlo + wo, &lds[12288 + lo]);
        }
        __syncthreads();
        bf16x8 ah[4], al[4], bh[4], bl[4];
        #pragma unroll
        for (int mt = 0; mt < 4; ++mt) {
            const int r = wm + mt * 16 + li;
            const int sw = (r & 3) ^ ((r >> 2) & 3);
            const int off = r * 32 + ((quad ^ sw) << 3);
            ah[mt] = *(const bf16x8*)&lds[off];
            al[mt] = *(const bf16x8*)&lds[4096 + off];
        }
        #pragma unroll
        for (int nt = 0; nt < 4; ++nt) {
            const int r = wn + nt * 16 + li;
            const int sw = (r & 3) ^ ((r >> 2) & 3);
            const int off = r * 32 + ((quad ^ sw) << 3);
            bh[nt] = *(const bf16x8*)&lds[8192 + off];
            bl[nt] = *(const bf16x8*)&lds[12288 + off];
        }
        #pragma unroll
        for (int mt = 0; mt < 4; ++mt)
            #pragma unroll
            for (int nt = 0; nt < 4; ++nt) {
                acc[mt][nt] = mfma16(ah[mt], bh[nt], acc[mt][nt]);
                acc[mt][nt] = mfma16(al[mt], bh[nt], acc[mt][nt]);
                acc[mt][nt] = mfma16(ah[mt], bl[nt], acc[mt][nt]);
            }
        __syncthreads();
    }

    #pragma unroll
    for (int mt = 0; mt < 4; ++mt) {
        const int rowb = m0 + wm + mt * 16 + quad * 4;
        #pragma unroll
        for (int nt = 0; nt < 4; ++nt) {
            const int col = n0 + wn + nt * 16 + li;
            const float bv = (mode != 0 && bias) ? bias[col] : 0.0f;
            #pragma unroll
            for (int r = 0; r < 4; ++r) {
                const size_t o = (size_t)(rowb + r) * 256 + col;
                const float v = acc[mt][nt][r];
                if (mode == 0) {
                    ((ushort*)outp)[o] = f2bf(v * scale);
                } else if (mode == 1) {
                    const float x = v + bv;
                    ((float*)outp)[o] = 1.0f / (1.0f + __expf(-x));
                } else {
                    ((float*)outp)[o] = v + bv;
                }
            }
        }
    }
}

// ---------------------------------------------------------------------------
// Launch
// ---------------------------------------------------------------------------
extern "C" void kernel_launch(void* const* d_in, const int* in_sizes, int n_in,
                              void* d_out, int out_size, void* d_ws, size_t ws_size,
                              hipStream_t stream) {
    const float* m    = (const float*)d_in[0];
    const unsigned* seqp = (const unsigned*)d_in[1];
    const unsigned* resp = (const unsigned*)d_in[2];
    const float* lng  = (const float*)d_in[3];
    const float* lnb  = (const float*)d_in[4];
    const float* Wq   = (const float*)d_in[5];
    const float* Wk   = (const float*)d_in[6];
    const float* Wv   = (const float*)d_in[7];
    const float* Wg   = (const float*)d_in[8];
    const float* bg   = (const float*)d_in[9];
    const float* Wo   = (const float*)d_in[10];
    const float* bo   = (const float*)d_in[11];
    float* out = (float*)d_out;

    char* p = (char*)d_ws;
    const size_t ABYTES = (size_t)Mrows * Dm * 2;      // 16.78 MB
    float* stats = (float*)p;  p += (size_t)Mrows * 2 * 4;
    ushort* Whi = (ushort*)p;  p += 5 * 65536 * 2;
    ushort* Wlo = (ushort*)p;  p += 5 * 65536 * 2;
    ushort* qb  = (ushort*)p;  p += ABYTES;
    ushort* kb  = (ushort*)p;  p += ABYTES;
    ushort* vb  = (ushort*)p;  p += ABYTES;
    ushort* gbf = (ushort*)p;  p += ABYTES;
    ushort* Ohi = (ushort*)p;  p += ABYTES;
    ushort* Olo = (ushort*)p;  p += ABYTES;
    float* qflag = (float*)p;  p += 1024;
    float* kbias = (float*)p;  p += 1024;

    ln_stats<<<Mrows / 4, 256, 0, stream>>>(m, stats);
    w_prep<<<dim3(64, 5), 256, 0, stream>>>(Wq, Wk, Wv, Wg, Wo, Whi, Wlo);
    mask_decode_kernel<<<1, 256, 0, stream>>>(seqp, resp, qflag, kbias);

    const float qscale = 0.17677669529663687f;   // 1/sqrt(32)
    qkvg_fused<<<dim3(2, 512), 256, 0, stream>>>(m, stats, lng, lnb, Whi, bg,
                                                 qb, kb, vb, gbf, qscale);

    attn2<<<dim3(8, 128), 256, 0, stream>>>(qb, kb, vb, gbf, qflag, kbias, Ohi, Olo);

    gemm_mfma<<<dim3(2, 256), 256, 0, stream>>>(Ohi, Olo, Whi + 4 * 65536, Wlo + 4 * 65536,
                                                bo, out, 1.0f, 2);
}

// Round 7
// 245.275 us; speedup vs baseline: 2.9351x; 1.0385x over previous
//
#include <hip/hip_runtime.h>
#include <math.h>

#define NEG_INF -10000.0f

typedef short bf16x8 __attribute__((ext_vector_type(8)));
typedef float f32x4 __attribute__((ext_vector_type(4)));

static constexpr int Dm = 256;   // model dim
static constexpr int Lm = 256;   // residues
static constexpr int Sm = 128;   // sequences
static constexpr int Mrows = Sm * Lm;  // 32768
static constexpr size_t HB = (size_t)Mrows * 32;  // head-plane stride (elems)

__device__ __forceinline__ ushort f2bf(float x) {
    unsigned u = __float_as_uint(x);
    unsigned r = (u + 0x7FFFu + ((u >> 16) & 1u)) >> 16;
    return (ushort)r;
}
__device__ __forceinline__ float bf2f(ushort h) {
    return __uint_as_float(((unsigned)h) << 16);
}
__device__ __forceinline__ void gload_lds16(const void* g, void* l) {
    __builtin_amdgcn_global_load_lds((__attribute__((address_space(1))) void*)g,
                                     (__attribute__((address_space(3))) void*)l,
                                     16, 0, 0);
}
__device__ __forceinline__ f32x4 mfma16(bf16x8 a, bf16x8 b, f32x4 c) {
    return __builtin_amdgcn_mfma_f32_16x16x32_bf16(a, b, c, 0, 0, 0);
}

// ---------------------------------------------------------------------------
// LayerNorm stats: one wave per row -> (mu, rsqrt(var+eps))
// ---------------------------------------------------------------------------
__global__ __launch_bounds__(256)
void ln_stats(const float* __restrict__ m, float* __restrict__ stats) {
    const int wid = threadIdx.x >> 6, lane = threadIdx.x & 63;
    const int row = (blockIdx.x << 2) + wid;
    const float4 a = ((const float4*)(m + (size_t)row * Dm))[lane];
    float s  = a.x + a.y + a.z + a.w;
    float ss = a.x*a.x + a.y*a.y + a.z*a.z + a.w*a.w;
    #pragma unroll
    for (int off = 32; off > 0; off >>= 1) {
        s  += __shfl_xor(s, off);
        ss += __shfl_xor(ss, off);
    }
    if (lane == 0) {
        const float mu = s * (1.0f / 256.0f);
        float2 st;
        st.x = mu;
        st.y = rsqrtf(ss * (1.0f / 256.0f) - mu * mu + 1e-5f);
        ((float2*)stats)[row] = st;
    }
}

// ---------------------------------------------------------------------------
// Split 5 weight matrices into bf16 hi/lo (stacked [5][256][256]).
// Mats 0-3: DESTINATION ROW PERMUTED within each 32-row head group:
//   actual channel ch -> storage pos p = (ch odd) ? 16 + ch/2 : ch/2.
// This makes qkvg's output tiles pair even/odd channels so lane li's two
// outputs are adjacent (dword stores). Outputs remain NATURAL order.
// Mat 4 (Wo) untouched.
// ---------------------------------------------------------------------------
__global__ __launch_bounds__(256)
void w_prep(const float* __restrict__ W0, const float* __restrict__ W1,
            const float* __restrict__ W2, const float* __restrict__ W3,
            const float* __restrict__ W4, ushort* __restrict__ Whi,
            ushort* __restrict__ Wlo) {
    const float* Ws[5] = {W0, W1, W2, W3, W4};
    const int mat = blockIdx.y;
    const size_t idx = ((size_t)blockIdx.x * 256 + threadIdx.x) * 4;
    const float4 v = *(const float4*)(Ws[mat] + idx);
    ushort4 hi, lo;
    hi.x = f2bf(v.x); lo.x = f2bf(v.x - bf2f(hi.x));
    hi.y = f2bf(v.y); lo.y = f2bf(v.y - bf2f(hi.y));
    hi.z = f2bf(v.z); lo.z = f2bf(v.z - bf2f(hi.z));
    hi.w = f2bf(v.w); lo.w = f2bf(v.w - bf2f(hi.w));
    const int row = (int)(idx >> 8), col = (int)(idx & 255);
    int drow = row;
    if (mat < 4) {
        const int ch = row & 31;
        const int p = (ch & 1) ? 16 + (ch >> 1) : (ch >> 1);
        drow = (row & ~31) | p;
    }
    const size_t o = (size_t)mat * 65536 + (size_t)drow * 256 + col;
    *(ushort4*)(Whi + o) = hi;
    *(ushort4*)(Wlo + o) = lo;
}

// ---------------------------------------------------------------------------
// Mask decode: qflag[q] = seq_pad[q] ? NEG_INF : 0 ; kbias[k] = res_pad[k] ? NEG_INF : 0
// Reference semantics: pad = (seq_pad[q] | res_pad[k]) * NEG_INF — an OR.
// Seq-padded query -> uniform bias -> softmax-invariant -> SELECT, not add.
// ---------------------------------------------------------------------------
__global__ void mask_decode_kernel(const unsigned* __restrict__ seq_raw,
                                   const unsigned* __restrict__ res_raw,
                                   float* __restrict__ qflag,
                                   float* __restrict__ kbias) {
    __shared__ unsigned long long sb[4], sf[4];
    __shared__ int enc;
    const int t = threadIdx.x;
    unsigned w = 0;
    if (t < 64)        w = seq_raw[t];
    else if (t < 128)  w = res_raw[t - 64];
    bool bad = (w != 0u) && (w != 1u) && (w != 0x3f800000u);
    bool isf = (w == 0x3f800000u);
    unsigned long long bm = __ballot(bad);
    unsigned long long fm = __ballot(isf);
    const int wid = t >> 6;
    if ((t & 63) == 0) { sb[wid] = bm; sf[wid] = fm; }
    __syncthreads();
    if (t == 0) {
        unsigned long long B = sb[0] | sb[1];
        unsigned long long F = sf[0] | sf[1];
        enc = B ? 2 : (F ? 1 : 0);
    }
    __syncthreads();
    const int e = enc;
    int sv, rv;
    if (e == 2) {
        const unsigned char* sp = (const unsigned char*)seq_raw;
        const unsigned char* rp = (const unsigned char*)res_raw;
        sv = sp[t]; rv = rp[t];
    } else if (e == 1) {
        sv = (((const float*)seq_raw)[t] != 0.0f);
        rv = (((const float*)res_raw)[t] != 0.0f);
    } else {
        sv = (seq_raw[t] != 0u);
        rv = (res_raw[t] != 0u);
    }
    qflag[t] = sv ? NEG_INF : 0.0f;
    kbias[t] = rv ? NEG_INF : 0.0f;
}

// ---------------------------------------------------------------------------
// Fused QKVG GEMM with LN fused into A staging.
// Block tile: M=64, N=512 (2 matrices), BK=32. grid (2, 512).
// W rows are even/odd-permuted (w_prep), so tiles (2h', 2h'+1) give lane li
// actual channels (2li, 2li+1) of head h' -> packed dword stores, outputs
// in NATURAL head-major [8][Mrows][32] layout.
// ---------------------------------------------------------------------------
__global__ __launch_bounds__(256, 2)
void qkvg_fused(const float* __restrict__ m, const float* __restrict__ stats,
                const float* __restrict__ lng, const float* __restrict__ lnb,
                const ushort* __restrict__ Whi, const float* __restrict__ bg,
                ushort* __restrict__ qb, ushort* __restrict__ kb,
                ushort* __restrict__ vb, ushort* __restrict__ gbf,
                float qscale) {
    __shared__ __align__(16) ushort Ah[64 * 32];
    __shared__ __align__(16) ushort Al[64 * 32];
    __shared__ __align__(16) ushort Wh[512 * 32];
    const int tid = threadIdx.x, lane = tid & 63, wave = tid >> 6;
    const int li = lane & 15, quad = lane >> 4;
    const int nb = blockIdx.x, m0 = blockIdx.y << 6;
    const int wm = (wave & 1) << 5;         // 0 / 32
    const int wn = (wave >> 1) << 8;        // 0 / 256
    const int mat = nb * 2 + (wave >> 1);   // which weight matrix this wave owns

    const int arow = tid >> 2, aslot = tid & 3;
    const int asw = (arow & 3) ^ ((arow >> 2) & 3);
    const float2 st = ((const float2*)stats)[m0 + arow];
    const float mu = st.x, rs = st.y;

    f32x4 zero = {0.f, 0.f, 0.f, 0.f};
    f32x4 acc[2][16];
    #pragma unroll
    for (int i = 0; i < 2; ++i)
        #pragma unroll
        for (int j = 0; j < 16; ++j) acc[i][j] = zero;

    for (int kt = 0; kt < 256; kt += 32) {
        #pragma unroll
        for (int i = 0; i < 8; ++i) {
            const int wrow = i * 64 + (tid >> 2);
            const int wsw = (wrow & 3) ^ ((wrow >> 2) & 3);
            const int g = (tid & 3) ^ wsw;
            gload_lds16(Whi + ((size_t)(nb * 512 + wrow) * 256 + kt + g * 8),
                        &Wh[i * 2048 + wave * 512]);
        }
        {
            const float* ap = m + (size_t)(m0 + arow) * 256 + kt + aslot * 8;
            const float4 v0 = *(const float4*)ap;
            const float4 v1 = *(const float4*)(ap + 4);
            const float4 g0 = *(const float4*)(lng + kt + aslot * 8);
            const float4 g1 = *(const float4*)(lng + kt + aslot * 8 + 4);
            const float4 b0 = *(const float4*)(lnb + kt + aslot * 8);
            const float4 b1 = *(const float4*)(lnb + kt + aslot * 8 + 4);
            float xs[8] = {v0.x, v0.y, v0.z, v0.w, v1.x, v1.y, v1.z, v1.w};
            float gs[8] = {g0.x, g0.y, g0.z, g0.w, g1.x, g1.y, g1.z, g1.w};
            float bs[8] = {b0.x, b0.y, b0.z, b0.w, b1.x, b1.y, b1.z, b1.w};
            bf16x8 hi8, lo8;
            #pragma unroll
            for (int e = 0; e < 8; ++e) {
                const float x = (xs[e] - mu) * rs * gs[e] + bs[e];
                const ushort h = f2bf(x);
                hi8[e] = (short)h;
                lo8[e] = (short)f2bf(x - bf2f(h));
            }
            const int adst = arow * 32 + ((aslot ^ asw) << 3);
            *(bf16x8*)&Ah[adst] = hi8;
            *(bf16x8*)&Al[adst] = lo8;
        }
        __syncthreads();
        bf16x8 ah[2], al[2];
        #pragma unroll
        for (int mt = 0; mt < 2; ++mt) {
            const int r = wm + mt * 16 + li;
            const int sw = (r & 3) ^ ((r >> 2) & 3);
            const int off = r * 32 + ((quad ^ sw) << 3);
            ah[mt] = *(const bf16x8*)&Ah[off];
            al[mt] = *(const bf16x8*)&Al[off];
        }
        #pragma unroll
        for (int nt = 0; nt < 16; ++nt) {
            const int rn = wn + nt * 16 + li;
            const int sw = (rn & 3) ^ ((rn >> 2) & 3);
            const bf16x8 bh = *(const bf16x8*)&Wh[rn * 32 + ((quad ^ sw) << 3)];
            acc[0][nt] = mfma16(ah[0], bh, acc[0][nt]);
            acc[0][nt] = mfma16(al[0], bh, acc[0][nt]);
            acc[1][nt] = mfma16(ah[1], bh, acc[1][nt]);
            acc[1][nt] = mfma16(al[1], bh, acc[1][nt]);
        }
        __syncthreads();
    }

    // Epilogue: tiles (2h', 2h'+1) = (even, odd) channels of head h'.
    ushort* outp = (mat == 0) ? qb : (mat == 1) ? kb : (mat == 2) ? vb : gbf;
    #pragma unroll
    for (int mt = 0; mt < 2; ++mt) {
        #pragma unroll
        for (int hh = 0; hh < 8; ++hh) {
            const int cE = hh * 32 + 2 * li;
            const float2 bg2 = *(const float2*)(bg + cE);
            #pragma unroll
            for (int r = 0; r < 4; ++r) {
                const int row = m0 + wm + mt * 16 + quad * 4 + r;
                float vE = acc[mt][2 * hh][r];
                float vO = acc[mt][2 * hh + 1][r];
                if (mat == 0) { vE *= qscale; vO *= qscale; }
                if (mat == 3) {
                    vE = 1.0f / (1.0f + __expf(-(vE + bg2.x)));
                    vO = 1.0f / (1.0f + __expf(-(vO + bg2.y)));
                }
                const unsigned u = (unsigned)f2bf(vE) | ((unsigned)f2bf(vO) << 16);
                *(unsigned*)&outp[(size_t)hh * HB + (size_t)row * 32 + 2 * li] = u;
            }
        }
    }
}

// ---------------------------------------------------------------------------
// Attention v5: head-major I/O, FULL bulk staging (K,Q,G via global_load_lds,
// V transposed), compact even/odd-paired Vt. Lane li's two output channels
// are 2li, 2li+1 -> dword G reads + dword O stores. LDS 64 KB.
// ---------------------------------------------------------------------------
__global__ __launch_bounds__(256, 2)
void attn2(const ushort* __restrict__ Qb, const ushort* __restrict__ Kb,
           const ushort* __restrict__ Vb, const ushort* __restrict__ Gb,
           const float* __restrict__ qflag, const float* __restrict__ kbias,
           ushort* __restrict__ Ohi, ushort* __restrict__ Olo) {
    __shared__ __align__(16) ushort Kl[8192];   // 16 KB swizzled K
    __shared__ __align__(16) ushort Ql[8192];   // 16 KB swizzled Q
    __shared__ __align__(16) ushort Gl[8192];   // 16 KB plain G
    __shared__ __align__(16) ushort Vt[8192];   // 16 KB paired/swizzled V^T
    const int h = blockIdx.x, s = blockIdx.y;
    const int tid = threadIdx.x, lane = tid & 63, wave = tid >> 6;
    const int li = lane & 15, quad = lane >> 4;
    const size_t base = (size_t)h * HB + (size_t)s * 8192;

    // --- bulk staging: K,Q (XOR-swizzled), G (plain) ---
    const int srow = tid >> 2, slot = tid & 3;
    const int sw0 = (srow & 3) ^ ((srow >> 2) & 3);
    const int gk0 = (slot ^ sw0) << 3;
    const int gp0 = slot << 3;
    #pragma unroll
    for (int i = 0; i < 4; ++i) {
        const int r = i * 64 + srow;
        const int dst = i * 2048 + wave * 512;
        gload_lds16(Kb + base + (size_t)r * 32 + gk0, &Kl[dst]);
        gload_lds16(Qb + base + (size_t)r * 32 + gk0, &Ql[dst]);
        gload_lds16(Gb + base + (size_t)r * 32 + gp0, &Gl[dst]);
    }
    // --- V transpose: thread = key. Paired compact layout:
    // Vt[vkb*1024 + (c&1)*512 + vq*128 + (((c>>1)^vsw)<<3) + vj]
    //   = V[key=32vkb+8vq+vj][c]   (tile0 = even channels, tile1 = odd)
    {
        const ushort* vrow = Vb + base + (size_t)tid * 32;
        bf16x8 vv0 = *(const bf16x8*)(vrow);
        bf16x8 vv1 = *(const bf16x8*)(vrow + 8);
        bf16x8 vv2 = *(const bf16x8*)(vrow + 16);
        bf16x8 vv3 = *(const bf16x8*)(vrow + 24);
        const int vkb = tid >> 5, vq = (tid >> 3) & 3, vj = tid & 7;
        const int vsw = (4 * vkb + vq) & 7;
        const int vbase = vkb * 1024 + vq * 128 + vj;
        #pragma unroll
        for (int c = 0; c < 32; ++c) {
            const short val = (c < 8) ? vv0[c & 7] : (c < 16) ? vv1[c & 7]
                            : (c < 24) ? vv2[c & 7] : vv3[c & 7];
            Vt[vbase + (c & 1) * 512 + (((c >> 1) ^ vsw) << 3)] = (ushort)val;
        }
    }
    __syncthreads();

    f32x4 zero = {0.f, 0.f, 0.f, 0.f};
    const int swq = (li & 3) ^ ((li >> 2) & 3);

    for (int chunk = 0; chunk < 4; ++chunk) {
        const int q0 = wave * 64 + chunk * 16;     // query base (residue)
        // Q B-frag from LDS: B[n=li][k=quad*8+j]
        const bf16x8 qf = *(const bf16x8*)&Ql[(q0 + li) * 32 + ((quad ^ swq) << 3)];
        // OR-mask select: seq-padded query -> ignore kbias entirely.
        const float kmul = (qflag[q0 + li] != 0.0f) ? 0.0f : 1.0f;

        // S^T tiles with permuted K rows (C/D layout == PV A-layout).
        f32x4 sc[16];
        #pragma unroll
        for (int t = 0; t < 16; ++t) {
            const int kr = (t >> 1) * 32 + ((li >> 2) << 3) + ((t & 1) << 2) + (li & 3);
            const int sw = (kr & 3) ^ ((kr >> 2) & 3);
            const bf16x8 kf = *(const bf16x8*)&Kl[kr * 32 + ((quad ^ sw) << 3)];
            sc[t] = mfma16(kf, qf, zero);
        }
        // sc[t][r] = S^T[key = (t>>1)*32 + 8*quad + 4*(t&1) + r][query = li]
        float mx = -1e30f;
        #pragma unroll
        for (int t = 0; t < 16; ++t) {
            const float4 kb4 = ((const float4*)kbias)[(t >> 1) * 8 + quad * 2 + (t & 1)];
            sc[t][0] += kmul * kb4.x;  sc[t][1] += kmul * kb4.y;
            sc[t][2] += kmul * kb4.z;  sc[t][3] += kmul * kb4.w;
            mx = fmaxf(mx, fmaxf(fmaxf(sc[t][0], sc[t][1]), fmaxf(sc[t][2], sc[t][3])));
        }
        mx = fmaxf(mx, __shfl_xor(mx, 16));
        mx = fmaxf(mx, __shfl_xor(mx, 32));
        float ls = 0.0f;
        #pragma unroll
        for (int t = 0; t < 16; ++t) {
            #pragma unroll
            for (int r = 0; r < 4; ++r) {
                const float p = __expf(sc[t][r] - mx);
                sc[t][r] = p;
                ls += p;
            }
        }
        ls += __shfl_xor(ls, 16);
        ls += __shfl_xor(ls, 32);

        // PV: pf comes straight from this lane's sc — no shuffles.
        f32x4 a0 = zero, a1 = zero;   // a0 -> channel 2li, a1 -> channel 2li+1
        #pragma unroll
        for (int kbk = 0; kbk < 8; ++kbk) {
            bf16x8 pf;
            pf[0] = (short)f2bf(sc[2 * kbk][0]);
            pf[1] = (short)f2bf(sc[2 * kbk][1]);
            pf[2] = (short)f2bf(sc[2 * kbk][2]);
            pf[3] = (short)f2bf(sc[2 * kbk][3]);
            pf[4] = (short)f2bf(sc[2 * kbk + 1][0]);
            pf[5] = (short)f2bf(sc[2 * kbk + 1][1]);
            pf[6] = (short)f2bf(sc[2 * kbk + 1][2]);
            pf[7] = (short)f2bf(sc[2 * kbk + 1][3]);
            const int vsw = (4 * kbk + quad) & 7;
            const bf16x8 v0 = *(const bf16x8*)&Vt[kbk * 1024 + quad * 128 + ((li ^ vsw) << 3)];
            const bf16x8 v1 = *(const bf16x8*)&Vt[kbk * 1024 + 512 + quad * 128 + ((li ^ vsw) << 3)];
            a0 = mfma16(pf, v0, a0);
            a1 = mfma16(pf, v1, a1);
        }
        // epilogue: O[q=4quad+r][2li], [2li+1]; gate; dword G read + dword O stores
        #pragma unroll
        for (int r = 0; r < 4; ++r) {
            const float lsr = __shfl(ls, 4 * quad + r);
            const float inv = 1.0f / lsr;
            const int rowq = q0 + 4 * quad + r;
            const size_t ro = base + (size_t)rowq * 32;
            const unsigned gu = *(const unsigned*)&Gl[rowq * 32 + 2 * li];
            const float g0 = bf2f((ushort)(gu & 0xFFFFu));
            const float g1 = bf2f((ushort)(gu >> 16));
            const float x0 = a0[r] * inv * g0;
            const float x1 = a1[r] * inv * g1;
            const ushort h0 = f2bf(x0), h1 = f2bf(x1);
            const unsigned uhi = (unsigned)h0 | ((unsigned)h1 << 16);
            const unsigned ulo = (unsigned)f2bf(x0 - bf2f(h0))
                               | ((unsigned)f2bf(x1 - bf2f(h1)) << 16);
            *(unsigned*)&Ohi[ro + 2 * li] = uhi;
            *(unsigned*)&Olo[ro + 2 * li] = ulo;
        }
    }
}

// ---------------------------------------------------------------------------
// Final GEMM: out = (Ohi+Olo) @ (Whi+Wlo)^T + bias, fp32 out.
// A (Ohi/Olo) is HEAD-MAJOR [8][Mrows][32]; k = head*32 + ch (natural order).
// ---------------------------------------------------------------------------
__global__ __launch_bounds__(256)
void gemm_mfma(const ushort* __restrict__ Ahi, const ushort* __restrict__ Alo,
               const ushort* __restrict__ Whi, const ushort* __restrict__ Wlo,
               const float* __restrict__ bias, void* __restrict__ outp,
               float scale, int mode) {
    __shared__ __align__(16) ushort lds[16384];
    const int tid = threadIdx.x;
    const int lane = tid & 63, wave = tid >> 6;
    const int li = lane & 15, quad = lane >> 4;
    const int m0 = blockIdx.y << 7, n0 = blockIdx.x << 7;
    const int wm = (wave >> 1) << 6, wn = (wave & 1) << 6;
    const int srow = tid >> 2, slot = tid & 3;
    const int sw0 = (srow & 3) ^ ((srow >> 2) & 3);
    const int gk0 = (slot ^ sw0) << 3;

    f32x4 zero = {0.f, 0.f, 0.f, 0.f};
    f32x4 acc[4][4];
    #pragma unroll
    for (int i = 0; i < 4; ++i)
        #pragma unroll
        for (int j = 0; j < 4; ++j) acc[i][j] = zero;

    for (int kt = 0; kt < 256; kt += 32) {
        const size_t hplane = (size_t)(kt >> 5) * HB;
        #pragma unroll
        for (int j = 0; j < 2; ++j) {
            const int r = j * 64 + srow;
            const size_t ao = hplane + (size_t)(m0 + r) * 32 + gk0;
            const size_t wo = (size_t)(n0 + r) * 256 + kt + gk0;
            const int lo = j * 2048 + wave * 512;
            gload_lds16(Ahi + ao, &lds[lo]);
            gload_lds16(Alo + ao, &lds[4096 + lo]);
            gload_lds16(Whi + wo, &lds[8192 + lo]);
            gload_lds16(Wlo + wo, &lds[12288 + lo]);
        }
        __syncthreads();
        bf16x8 ah[4], al[4], bh[4], bl[4];
        #pragma unroll
        for (int mt = 0; mt < 4; ++mt) {
            const int r = wm + mt * 16 + li;
            const int sw = (r & 3) ^ ((r >> 2) & 3);
            const int off = r * 32 + ((quad ^ sw) << 3);
            ah[mt] = *(const bf16x8*)&lds[off];
            al[mt] = *(const bf16x8*)&lds[4096 + off];
        }
        #pragma unroll
        for (int nt = 0; nt < 4; ++nt) {
            const int r = wn + nt * 16 + li;
            const int sw = (r & 3) ^ ((r >> 2) & 3);
            const int off = r * 32 + ((quad ^ sw) << 3);
            bh[nt] = *(const bf16x8*)&lds[8192 + off];
            bl[nt] = *(const bf16x8*)&lds[12288 + off];
        }
        #pragma unroll
        for (int mt = 0; mt < 4; ++mt)
            #pragma unroll
            for (int nt = 0; nt < 4; ++nt) {
                acc[mt][nt] = mfma16(ah[mt], bh[nt], acc[mt][nt]);
                acc[mt][nt] = mfma16(al[mt], bh[nt], acc[mt][nt]);
                acc[mt][nt] = mfma16(ah[mt], bl[nt], acc[mt][nt]);
            }
        __syncthreads();
    }

    #pragma unroll
    for (int mt = 0; mt < 4; ++mt) {
        const int rowb = m0 + wm + mt * 16 + quad * 4;
        #pragma unroll
        for (int nt = 0; nt < 4; ++nt) {
            const int col = n0 + wn + nt * 16 + li;
            const float bv = (mode != 0 && bias) ? bias[col] : 0.0f;
            #pragma unroll
            for (int r = 0; r < 4; ++r) {
                const size_t o = (size_t)(rowb + r) * 256 + col;
                const float v = acc[mt][nt][r];
                if (mode == 0) {
                    ((ushort*)outp)[o] = f2bf(v * scale);
                } else if (mode == 1) {
                    const float x = v + bv;
                    ((float*)outp)[o] = 1.0f / (1.0f + __expf(-x));
                } else {
                    ((float*)outp)[o] = v + bv;
                }
            }
        }
    }
}

// ---------------------------------------------------------------------------
// Launch
// ---------------------------------------------------------------------------
extern "C" void kernel_launch(void* const* d_in, const int* in_sizes, int n_in,
                              void* d_out, int out_size, void* d_ws, size_t ws_size,
                              hipStream_t stream) {
    const float* m    = (const float*)d_in[0];
    const unsigned* seqp = (const unsigned*)d_in[1];
    const unsigned* resp = (const unsigned*)d_in[2];
    const float* lng  = (const float*)d_in[3];
    const float* lnb  = (const float*)d_in[4];
    const float* Wq   = (const float*)d_in[5];
    const float* Wk   = (const float*)d_in[6];
    const float* Wv   = (const float*)d_in[7];
    const float* Wg   = (const float*)d_in[8];
    const float* bg   = (const float*)d_in[9];
    const float* Wo   = (const float*)d_in[10];
    const float* bo   = (const float*)d_in[11];
    float* out = (float*)d_out;

    char* p = (char*)d_ws;
    const size_t ABYTES = (size_t)Mrows * Dm * 2;      // 16.78 MB
    float* stats = (float*)p;  p += (size_t)Mrows * 2 * 4;
    ushort* Whi = (ushort*)p;  p += 5 * 65536 * 2;
    ushort* Wlo = (ushort*)p;  p += 5 * 65536 * 2;
    ushort* qb  = (ushort*)p;  p += ABYTES;
    ushort* kb  = (ushort*)p;  p += ABYTES;
    ushort* vb  = (ushort*)p;  p += ABYTES;
    ushort* gbf = (ushort*)p;  p += ABYTES;
    ushort* Ohi = (ushort*)p;  p += ABYTES;
    ushort* Olo = (ushort*)p;  p += ABYTES;
    float* qflag = (float*)p;  p += 1024;
    float* kbias = (float*)p;  p += 1024;

    ln_stats<<<Mrows / 4, 256, 0, stream>>>(m, stats);
    w_prep<<<dim3(64, 5), 256, 0, stream>>>(Wq, Wk, Wv, Wg, Wo, Whi, Wlo);
    mask_decode_kernel<<<1, 256, 0, stream>>>(seqp, resp, qflag, kbias);

    const float qscale = 0.17677669529663687f;   // 1/sqrt(32)
    qkvg_fused<<<dim3(2, 512), 256, 0, stream>>>(m, stats, lng, lnb, Whi, bg,
                                                 qb, kb, vb, gbf, qscale);

    attn2<<<dim3(8, 128), 256, 0, stream>>>(qb, kb, vb, gbf, qflag, kbias, Ohi, Olo);

    gemm_mfma<<<dim3(2, 256), 256, 0, stream>>>(Ohi, Olo, Whi + 4 * 65536, Wlo + 4 * 65536,
                                                bo, out, 1.0f, 2);
}